// Round 1
// baseline (1125.808 us; speedup 1.0000x reference)
//
#include <hip/hip_runtime.h>
#include <math.h>

#define FIN 4
#define HID 32

// ---------------------------------------------------------------------------
// 1) weighted in-degree: deg[dst[e]] += w[e]
__global__ void deg_kernel(const int* __restrict__ dst, const float* __restrict__ w,
                           float* __restrict__ deg, int E) {
    int e = blockIdx.x * blockDim.x + threadIdx.x;
    if (e < E) atomicAdd(&deg[dst[e]], w[e]);
}

// ---------------------------------------------------------------------------
// 2) dinv = rsqrt(deg + 1) (self-loop weight 1); init aggA with self-loop term
//    x[i] * dinv[i]^2; also accumulate per-graph node counts.
__global__ void dinv_init_kernel(const float* __restrict__ deg, float* __restrict__ dinv,
                                 const float* __restrict__ x, float* __restrict__ aggA,
                                 const int* __restrict__ batch, float* __restrict__ cnt,
                                 int n) {
    int i = blockIdx.x * blockDim.x + threadIdx.x;
    if (i >= n) return;
    float d  = deg[i] + 1.0f;           // always > 0 (self-loop)
    float di = rsqrtf(d);
    dinv[i]  = di;
    float d2 = di * di;
    float4 xv = *reinterpret_cast<const float4*>(x + (size_t)i * FIN);
    float4 av = make_float4(xv.x * d2, xv.y * d2, xv.z * d2, xv.w * d2);
    *reinterpret_cast<float4*>(aggA + (size_t)i * FIN) = av;
    atomicAdd(&cnt[batch[i]], 1.0f);
}

// ---------------------------------------------------------------------------
// 3) edge norm = dinv[src] * w * dinv[dst]
__global__ void norm_kernel(const int* __restrict__ src, const int* __restrict__ dst,
                            const float* __restrict__ w, const float* __restrict__ dinv,
                            float* __restrict__ norm, int E) {
    int e = blockIdx.x * blockDim.x + threadIdx.x;
    if (e < E) norm[e] = dinv[src[e]] * w[e] * dinv[dst[e]];
}

// ---------------------------------------------------------------------------
// 4) layer-1 scatter on RAW x (4 dims): aggA[dst] += x[src] * norm
__global__ void scatter1_kernel(const int* __restrict__ src, const int* __restrict__ dst,
                                const float* __restrict__ norm, const float* __restrict__ x,
                                float* __restrict__ aggA, int E) {
    int e = blockIdx.x * blockDim.x + threadIdx.x;
    if (e >= E) return;
    int s = src[e], d = dst[e];
    float nv = norm[e];
    float4 xv = *reinterpret_cast<const float4*>(x + (size_t)s * FIN);
    float* ap = aggA + (size_t)d * FIN;
    atomicAdd(ap + 0, xv.x * nv);
    atomicAdd(ap + 1, xv.y * nv);
    atomicAdd(ap + 2, xv.z * nv);
    atomicAdd(ap + 3, xv.w * nv);
}

// ---------------------------------------------------------------------------
// 5) transform1: h1 = relu(aggA @ W1 + b1); seed aggB with layer-2 self-loop
//    term h1 * dinv^2.   One thread per (node, k).
__global__ void transform1_kernel(const float* __restrict__ aggA, const float* __restrict__ W1,
                                  const float* __restrict__ b1, const float* __restrict__ dinv,
                                  float* __restrict__ h1, float* __restrict__ aggB, int n) {
    int t = blockIdx.x * blockDim.x + threadIdx.x;
    if (t >= n * HID) return;
    int i = t / HID;
    int k = t - i * HID;
    const float* ar = aggA + (size_t)i * FIN;
    float acc = b1[k];
    #pragma unroll
    for (int j = 0; j < FIN; ++j) acc += ar[j] * W1[j * HID + k];
    float h = acc > 0.0f ? acc : 0.0f;
    h1[t] = h;
    float di = dinv[i];
    aggB[t] = h * di * di;
}

// ---------------------------------------------------------------------------
// 6) layer-2 scatter (32 dims): 8 threads per edge, float4 chunks.
__global__ void scatter2_kernel(const int* __restrict__ src, const int* __restrict__ dst,
                                const float* __restrict__ norm, const float* __restrict__ h1,
                                float* __restrict__ aggB, int E) {
    int t = blockIdx.x * blockDim.x + threadIdx.x;
    int e = t >> 3;
    if (e >= E) return;
    int r = (t & 7) * 4;
    int s = src[e], d = dst[e];
    float nv = norm[e];
    float4 hv = *reinterpret_cast<const float4*>(h1 + (size_t)s * HID + r);
    float* ap = aggB + (size_t)d * HID + r;
    atomicAdd(ap + 0, hv.x * nv);
    atomicAdd(ap + 1, hv.y * nv);
    atomicAdd(ap + 2, hv.z * nv);
    atomicAdd(ap + 3, hv.w * nv);
}

// ---------------------------------------------------------------------------
// 7) transform2 + relu + mean-pool accumulate (h2 never materialized)
__global__ void transform2_pool_kernel(const float* __restrict__ aggB, const float* __restrict__ W2,
                                       const float* __restrict__ b2, const int* __restrict__ batch,
                                       float* __restrict__ sums, int n) {
    int t = blockIdx.x * blockDim.x + threadIdx.x;
    if (t >= n * HID) return;
    int i = t / HID;
    int k = t - i * HID;
    const float* br = aggB + (size_t)i * HID;
    float acc = b2[k];
    #pragma unroll
    for (int j = 0; j < HID; ++j) acc += br[j] * W2[j * HID + k];
    float h = acc > 0.0f ? acc : 0.0f;
    atomicAdd(&sums[(size_t)batch[i] * HID + k], h);
}

// ---------------------------------------------------------------------------
// 8) heads: mean, two 32-dot products, sigmoids
__global__ void heads_kernel(const float* __restrict__ sums, const float* __restrict__ cnt,
                             const float* __restrict__ Wo, const float* __restrict__ bo,
                             const float* __restrict__ Wb, const float* __restrict__ bb,
                             float* __restrict__ out, int G) {
    int g = blockIdx.x * blockDim.x + threadIdx.x;
    if (g >= G) return;
    float c = cnt[g];
    float inv = 1.0f / fmaxf(c, 1.0f);
    const float* sr = sums + (size_t)g * HID;
    float dot_o = bo[0], dot_b = bb[0];
    #pragma unroll
    for (int k = 0; k < HID; ++k) {
        float m = sr[k] * inv;
        dot_o += m * Wo[k];
        dot_b += m * Wb[k];
    }
    out[g]     = 1.0f / (1.0f + expf(-dot_o));
    out[G + g] = 1.0f / (1.0f + expf(-dot_b));
}

// ---------------------------------------------------------------------------
extern "C" void kernel_launch(void* const* d_in, const int* in_sizes, int n_in,
                              void* d_out, int out_size, void* d_ws, size_t ws_size,
                              hipStream_t stream) {
    const float* x     = (const float*)d_in[0];
    const int*   ei    = (const int*)d_in[1];
    const float* ew    = (const float*)d_in[2];
    const int*   batch = (const int*)d_in[3];
    // d_in[4] = num_graphs scalar (device); we derive G from out_size instead.
    const float* W1 = (const float*)d_in[5];
    const float* b1 = (const float*)d_in[6];
    const float* W2 = (const float*)d_in[7];
    const float* b2 = (const float*)d_in[8];
    const float* Wo = (const float*)d_in[9];
    const float* bo = (const float*)d_in[10];
    const float* Wb = (const float*)d_in[11];
    const float* bb = (const float*)d_in[12];
    float* out = (float*)d_out;

    const int n = in_sizes[0] / FIN;      // 100000
    const int E = in_sizes[2];            // 1600000
    const int G = out_size / 2;           // 16384
    const int* src = ei;
    const int* dst = ei + E;

    // workspace layout (floats)
    float* ws   = (float*)d_ws;
    float* deg  = ws;                        // n
    float* dinv = deg  + n;                  // n
    float* norm = dinv + n;                  // E
    float* aggA = norm + E;                  // n*FIN
    float* h1   = aggA + (size_t)n * FIN;    // n*HID
    float* aggB = h1   + (size_t)n * HID;    // n*HID
    float* sums = aggB + (size_t)n * HID;    // G*HID
    float* cnt  = sums + (size_t)G * HID;    // G   (contiguous with sums)

    hipMemsetAsync(deg,  0, (size_t)n * sizeof(float), stream);
    hipMemsetAsync(sums, 0, ((size_t)G * HID + G) * sizeof(float), stream);

    const int B = 256;
    deg_kernel<<<(E + B - 1) / B, B, 0, stream>>>(dst, ew, deg, E);
    dinv_init_kernel<<<(n + B - 1) / B, B, 0, stream>>>(deg, dinv, x, aggA, batch, cnt, n);
    norm_kernel<<<(E + B - 1) / B, B, 0, stream>>>(src, dst, ew, dinv, norm, E);
    scatter1_kernel<<<(E + B - 1) / B, B, 0, stream>>>(src, dst, norm, x, aggA, E);
    transform1_kernel<<<((size_t)n * HID + B - 1) / B, B, 0, stream>>>(aggA, W1, b1, dinv, h1, aggB, n);
    scatter2_kernel<<<((size_t)E * 8 + B - 1) / B, B, 0, stream>>>(src, dst, norm, h1, aggB, E);
    transform2_pool_kernel<<<((size_t)n * HID + B - 1) / B, B, 0, stream>>>(aggB, W2, b2, batch, sums, n);
    heads_kernel<<<(G + B - 1) / B, B, 0, stream>>>(sums, cnt, Wo, bo, Wb, bb, out, G);
}

// Round 2
// 398.854 us; speedup vs baseline: 2.8226x; 2.8226x over previous
//
#include <hip/hip_runtime.h>
#include <math.h>

#define FIN 4
#define HID 32
#define SCAN_B 256

// ---------------------------------------------------------------------------
// 1) histogram: count[dst]++ and weighted degree wdeg[dst] += w
__global__ void hist_kernel(const int* __restrict__ dst, const float* __restrict__ w,
                            int* __restrict__ count, float* __restrict__ wdeg, int E) {
    int e = blockIdx.x * blockDim.x + threadIdx.x;
    if (e >= E) return;
    int d = dst[e];
    atomicAdd(&count[d], 1);
    atomicAdd(&wdeg[d], w[e]);
}

// ---------------------------------------------------------------------------
// 2) dinv = rsqrt(wdeg + 1) (self-loop weight 1); per-graph node counts
__global__ void dinv_kernel(const float* __restrict__ wdeg, float* __restrict__ dinv,
                            const int* __restrict__ batch, float* __restrict__ cnt, int n) {
    int i = blockIdx.x * blockDim.x + threadIdx.x;
    if (i >= n) return;
    dinv[i] = rsqrtf(wdeg[i] + 1.0f);
    atomicAdd(&cnt[batch[i]], 1.0f);
}

// ---------------------------------------------------------------------------
// 3a) per-block inclusive scan of count
__global__ void scan1_kernel(const int* __restrict__ count, int* __restrict__ bscan,
                             int* __restrict__ bsum, int n) {
    __shared__ int s[SCAN_B];
    int i = blockIdx.x * SCAN_B + threadIdx.x;
    int v = (i < n) ? count[i] : 0;
    s[threadIdx.x] = v;
    __syncthreads();
    for (int off = 1; off < SCAN_B; off <<= 1) {
        int t = (threadIdx.x >= off) ? s[threadIdx.x - off] : 0;
        __syncthreads();
        s[threadIdx.x] += t;
        __syncthreads();
    }
    if (i < n) bscan[i] = s[threadIdx.x];
    if (threadIdx.x == SCAN_B - 1) bsum[blockIdx.x] = s[threadIdx.x];
}

// 3b) single-block inclusive scan of block sums (in place), carry loop
__global__ void scan2_kernel(int* __restrict__ data, int nb) {
    __shared__ int s[512];
    __shared__ int carry;
    if (threadIdx.x == 0) carry = 0;
    __syncthreads();
    for (int base = 0; base < nb; base += 512) {
        int idx = base + threadIdx.x;
        int v = (idx < nb) ? data[idx] : 0;
        s[threadIdx.x] = v;
        __syncthreads();
        for (int off = 1; off < 512; off <<= 1) {
            int t = (threadIdx.x >= off) ? s[threadIdx.x - off] : 0;
            __syncthreads();
            s[threadIdx.x] += t;
            __syncthreads();
        }
        int incl = s[threadIdx.x] + carry;
        if (idx < nb) data[idx] = incl;
        __syncthreads();
        if (threadIdx.x == 511) carry = incl;
        __syncthreads();
    }
}

// 3c) rowptr[i] (exclusive) = bscan[i] - count[i] + blockOffset; cursor copy
__global__ void scan3_kernel(const int* __restrict__ bscan, const int* __restrict__ count,
                             const int* __restrict__ bsumscan, int* __restrict__ rowptr,
                             int* __restrict__ cursor, int n) {
    int i = blockIdx.x * SCAN_B + threadIdx.x;
    if (i >= n) return;
    int off = (blockIdx.x == 0) ? 0 : bsumscan[blockIdx.x - 1];
    int r = bscan[i] - count[i] + off;
    rowptr[i] = r;
    cursor[i] = r;
}

// ---------------------------------------------------------------------------
// 4) fill CSR: (src, norm) records grouped by dst; norm = dinv[s]*w*dinv[d]
__global__ void fill_kernel(const int* __restrict__ src, const int* __restrict__ dst,
                            const float* __restrict__ w, const float* __restrict__ dinv,
                            int* __restrict__ cursor, int2* __restrict__ csr, int E) {
    int e = blockIdx.x * blockDim.x + threadIdx.x;
    if (e >= E) return;
    int s = src[e], d = dst[e];
    float nv = dinv[s] * w[e] * dinv[d];
    int pos = atomicAdd(&cursor[d], 1);
    csr[pos] = make_int2(s, __float_as_int(nv));
}

// ---------------------------------------------------------------------------
// 5) layer 1 fused: gather raw x (4 dims) + self-loop, then h1 = relu(agg@W1+b1)
__global__ void layer1_kernel(const float* __restrict__ x, const int* __restrict__ rowptr,
                              const int* __restrict__ count, const int2* __restrict__ csr,
                              const float* __restrict__ dinv, const float* __restrict__ W1,
                              const float* __restrict__ b1, float* __restrict__ h1, int n) {
    __shared__ float sW[FIN * HID];
    __shared__ float sb[HID];
    int t = threadIdx.x;
    if (t < FIN * HID) sW[t] = W1[t];
    if (t < HID) sb[t] = b1[t];
    __syncthreads();
    int i = blockIdx.x * blockDim.x + t;
    if (i >= n) return;
    float di = dinv[i];
    float d2 = di * di;
    float4 a = *reinterpret_cast<const float4*>(x + (size_t)i * FIN);
    a.x *= d2; a.y *= d2; a.z *= d2; a.w *= d2;
    int beg = rowptr[i], c = count[i];
    for (int j = 0; j < c; ++j) {
        int2 rec = csr[beg + j];
        float nv = __int_as_float(rec.y);
        float4 xs = *reinterpret_cast<const float4*>(x + (size_t)rec.x * FIN);
        a.x += nv * xs.x; a.y += nv * xs.y; a.z += nv * xs.z; a.w += nv * xs.w;
    }
    float* hp = h1 + (size_t)i * HID;
    #pragma unroll
    for (int k = 0; k < HID; k += 4) {
        float4 hv;
        hv.x = fmaxf(sb[k+0] + a.x*sW[0*HID+k+0] + a.y*sW[1*HID+k+0] + a.z*sW[2*HID+k+0] + a.w*sW[3*HID+k+0], 0.f);
        hv.y = fmaxf(sb[k+1] + a.x*sW[0*HID+k+1] + a.y*sW[1*HID+k+1] + a.z*sW[2*HID+k+1] + a.w*sW[3*HID+k+1], 0.f);
        hv.z = fmaxf(sb[k+2] + a.x*sW[0*HID+k+2] + a.y*sW[1*HID+k+2] + a.z*sW[2*HID+k+2] + a.w*sW[3*HID+k+2], 0.f);
        hv.w = fmaxf(sb[k+3] + a.x*sW[0*HID+k+3] + a.y*sW[1*HID+k+3] + a.z*sW[2*HID+k+3] + a.w*sW[3*HID+k+3], 0.f);
        *reinterpret_cast<float4*>(hp + k) = hv;
    }
}

// ---------------------------------------------------------------------------
// 6) layer 2 fused: gather h1 (32 dims, 8 lanes/node) + W2 + relu + mean-pool acc
__global__ void layer2_kernel(const float* __restrict__ h1, const int* __restrict__ rowptr,
                              const int* __restrict__ count, const int2* __restrict__ csr,
                              const float* __restrict__ dinv, const float* __restrict__ W2,
                              const float* __restrict__ b2, const int* __restrict__ batch,
                              float* __restrict__ sums, int n) {
    __shared__ float sW[HID * HID];       // 4 KB
    __shared__ float sb[HID];
    __shared__ float sAgg[32][HID + 1];   // +1 pad: bank-conflict-free
    int t = threadIdx.x;
    for (int q = t; q < HID * HID; q += blockDim.x) sW[q] = W2[q];
    if (t < HID) sb[t] = b2[t];
    __syncthreads();
    int nib = t >> 3;          // node-in-block 0..31
    int l   = t & 7;           // dim-quad lane 0..7
    int i = blockIdx.x * 32 + nib;
    bool valid = i < n;
    float4 a = make_float4(0.f, 0.f, 0.f, 0.f);
    if (valid) {
        const float4* h4 = reinterpret_cast<const float4*>(h1);
        float di = dinv[i];
        float d2 = di * di;
        a = h4[(size_t)i * 8 + l];
        a.x *= d2; a.y *= d2; a.z *= d2; a.w *= d2;
        int beg = rowptr[i], c = count[i];
        for (int j = 0; j < c; ++j) {
            int2 rec = csr[beg + j];
            float nv = __int_as_float(rec.y);
            float4 hs = h4[(size_t)rec.x * 8 + l];
            a.x += nv * hs.x; a.y += nv * hs.y; a.z += nv * hs.z; a.w += nv * hs.w;
        }
    }
    sAgg[nib][l * 4 + 0] = a.x;
    sAgg[nib][l * 4 + 1] = a.y;
    sAgg[nib][l * 4 + 2] = a.z;
    sAgg[nib][l * 4 + 3] = a.w;
    __syncthreads();
    if (valid) {
        float* sp = sums + (size_t)batch[i] * HID;
        #pragma unroll
        for (int kk = 0; kk < 4; ++kk) {
            int k = l * 4 + kk;
            float acc = sb[k];
            #pragma unroll
            for (int j = 0; j < HID; ++j) acc += sAgg[nib][j] * sW[j * HID + k];
            acc = fmaxf(acc, 0.f);
            atomicAdd(&sp[k], acc);
        }
    }
}

// ---------------------------------------------------------------------------
// 7) heads: mean, two 32-dot products, sigmoids
__global__ void heads_kernel(const float* __restrict__ sums, const float* __restrict__ cnt,
                             const float* __restrict__ Wo, const float* __restrict__ bo,
                             const float* __restrict__ Wb, const float* __restrict__ bb,
                             float* __restrict__ out, int G) {
    int g = blockIdx.x * blockDim.x + threadIdx.x;
    if (g >= G) return;
    float inv = 1.0f / fmaxf(cnt[g], 1.0f);
    const float* sr = sums + (size_t)g * HID;
    float dot_o = bo[0], dot_b = bb[0];
    #pragma unroll
    for (int k = 0; k < HID; ++k) {
        float m = sr[k] * inv;
        dot_o += m * Wo[k];
        dot_b += m * Wb[k];
    }
    out[g]     = 1.0f / (1.0f + expf(-dot_o));
    out[G + g] = 1.0f / (1.0f + expf(-dot_b));
}

// ---------------------------------------------------------------------------
extern "C" void kernel_launch(void* const* d_in, const int* in_sizes, int n_in,
                              void* d_out, int out_size, void* d_ws, size_t ws_size,
                              hipStream_t stream) {
    const float* x     = (const float*)d_in[0];
    const int*   ei    = (const int*)d_in[1];
    const float* ew    = (const float*)d_in[2];
    const int*   batch = (const int*)d_in[3];
    const float* W1 = (const float*)d_in[5];
    const float* b1 = (const float*)d_in[6];
    const float* W2 = (const float*)d_in[7];
    const float* b2 = (const float*)d_in[8];
    const float* Wo = (const float*)d_in[9];
    const float* bo = (const float*)d_in[10];
    const float* Wb = (const float*)d_in[11];
    const float* bb = (const float*)d_in[12];
    float* out = (float*)d_out;

    const int n = in_sizes[0] / FIN;   // 100000
    const int E = in_sizes[2];         // 1600000
    const int G = out_size / 2;        // 16384
    const int* src = ei;
    const int* dst = ei + E;
    const int n4 = (n + 3) & ~3;       // alignment-padded node count
    const int nb = (n + SCAN_B - 1) / SCAN_B;
    const int nbp = (nb + 511) & ~511; // padded block-sum count

    // workspace layout (4-byte elements; all region sizes multiple of 4 -> 16B aligned)
    char* wsb = (char*)d_ws;
    int2*  csr    = (int2*)wsb;                           // E int2 (8B each)
    int*   count  = (int*)(wsb + (size_t)E * 8);          // n4  -- zeroed region start
    float* wdeg   = (float*)(count + n4);                 // n4
    float* sums   = wdeg + n4;                            // G*HID
    float* cnt    = sums + (size_t)G * HID;               // G   -- zeroed region end
    float* dinv   = cnt + G;                              // n4
    int*   rowptr = (int*)(dinv + n4);                    // n4
    int*   cursor = rowptr + n4;                          // n4
    int*   bscan  = cursor + n4;                          // n4
    int*   bsum   = bscan + n4;                           // nbp
    float* h1     = (float*)(bsum + nbp);                 // n*HID

    hipMemsetAsync(count, 0, ((size_t)2 * n4 + (size_t)G * HID + G) * sizeof(float), stream);

    const int B = 256;
    hist_kernel <<<(E + B - 1) / B, B, 0, stream>>>(dst, ew, count, wdeg, E);
    dinv_kernel <<<(n + B - 1) / B, B, 0, stream>>>(wdeg, dinv, batch, cnt, n);
    scan1_kernel<<<nb, SCAN_B, 0, stream>>>(count, bscan, bsum, n);
    scan2_kernel<<<1, 512, 0, stream>>>(bsum, nb);
    scan3_kernel<<<nb, SCAN_B, 0, stream>>>(bscan, count, bsum, rowptr, cursor, n);
    fill_kernel <<<(E + B - 1) / B, B, 0, stream>>>(src, dst, ew, dinv, cursor, csr, E);
    layer1_kernel<<<(n + B - 1) / B, B, 0, stream>>>(x, rowptr, count, csr, dinv, W1, b1, h1, n);
    layer2_kernel<<<(n + 31) / 32, B, 0, stream>>>(h1, rowptr, count, csr, dinv, W2, b2, batch, sums, n);
    heads_kernel<<<(G + B - 1) / B, B, 0, stream>>>(sums, cnt, Wo, bo, Wb, bb, out, G);
}

// Round 3
// 198.365 us; speedup vs baseline: 5.6754x; 2.0107x over previous
//
#include <hip/hip_runtime.h>
#include <math.h>

#define FIN 4
#define HID 32
#define SCAN_B 256

__device__ __forceinline__ unsigned pack_bf16x2(float a, float b) {
    unsigned ua = __float_as_uint(a); ua += 0x7FFF + ((ua >> 16) & 1);
    unsigned ub = __float_as_uint(b); ub += 0x7FFF + ((ub >> 16) & 1);
    return (ua >> 16) | (ub & 0xFFFF0000u);
}

// ---------------------------------------------------------------------------
// 1) packed histogram: one u64 atomic carries (count<<40 | wdeg_fix24);
//    the RETURN value gives this edge's rank within its dst bucket.
__global__ void hist_kernel(const int* __restrict__ dst, const float* __restrict__ w,
                            unsigned long long* __restrict__ packed, int* __restrict__ rank,
                            int E) {
    int e = blockIdx.x * blockDim.x + threadIdx.x;
    if (e >= E) return;
    int d = dst[e];
    unsigned long long wfix = (unsigned long long)(w[e] * 16777216.0f + 0.5f);
    unsigned long long old = atomicAdd(&packed[d], (1ull << 40) | wfix);
    rank[e] = (int)(old >> 40);
}

// ---------------------------------------------------------------------------
// 2) unpack: dinv = rsqrt(wdeg + 1); counti for scan
__global__ void dinv_kernel(const unsigned long long* __restrict__ packed,
                            float* __restrict__ dinv, int* __restrict__ counti, int n) {
    int i = blockIdx.x * blockDim.x + threadIdx.x;
    if (i >= n) return;
    unsigned long long p = packed[i];
    float wdeg = (float)(p & ((1ull << 40) - 1)) * (1.0f / 16777216.0f);
    dinv[i] = rsqrtf(wdeg + 1.0f);
    counti[i] = (int)(p >> 40);
}

// ---------------------------------------------------------------------------
// 3) scans for rowptr (exclusive prefix of counti)
__global__ void scan1_kernel(const int* __restrict__ count, int* __restrict__ bscan,
                             int* __restrict__ bsum, int n) {
    __shared__ int s[SCAN_B];
    int i = blockIdx.x * SCAN_B + threadIdx.x;
    int v = (i < n) ? count[i] : 0;
    s[threadIdx.x] = v;
    __syncthreads();
    for (int off = 1; off < SCAN_B; off <<= 1) {
        int t = (threadIdx.x >= off) ? s[threadIdx.x - off] : 0;
        __syncthreads();
        s[threadIdx.x] += t;
        __syncthreads();
    }
    if (i < n) bscan[i] = s[threadIdx.x];
    if (threadIdx.x == SCAN_B - 1) bsum[blockIdx.x] = s[threadIdx.x];
}

__global__ void scan2_kernel(int* __restrict__ data, int nb) {
    __shared__ int s[512];
    __shared__ int carry;
    if (threadIdx.x == 0) carry = 0;
    __syncthreads();
    for (int base = 0; base < nb; base += 512) {
        int idx = base + threadIdx.x;
        int v = (idx < nb) ? data[idx] : 0;
        s[threadIdx.x] = v;
        __syncthreads();
        for (int off = 1; off < 512; off <<= 1) {
            int t = (threadIdx.x >= off) ? s[threadIdx.x - off] : 0;
            __syncthreads();
            s[threadIdx.x] += t;
            __syncthreads();
        }
        int incl = s[threadIdx.x] + carry;
        if (idx < nb) data[idx] = incl;
        __syncthreads();
        if (threadIdx.x == 511) carry = incl;
        __syncthreads();
    }
}

__global__ void scan3_kernel(const int* __restrict__ bscan, const int* __restrict__ count,
                             const int* __restrict__ bsumscan, int* __restrict__ rowptr, int n) {
    int i = blockIdx.x * SCAN_B + threadIdx.x;
    if (i >= n) return;
    int off = (blockIdx.x == 0) ? 0 : bsumscan[blockIdx.x - 1];
    rowptr[i] = bscan[i] - count[i] + off;
}

// ---------------------------------------------------------------------------
// 4) graph segment boundaries from sorted batch (gstart[g..G], no atomics)
__global__ void bounds_kernel(const int* __restrict__ batch, int* __restrict__ gstart,
                              int n, int G) {
    int i = blockIdx.x * blockDim.x + threadIdx.x;
    if (i >= n) return;
    int b = batch[i];
    if (i == 0) {
        for (int g = 0; g <= b; ++g) gstart[g] = 0;
    } else {
        int p = batch[i - 1];
        for (int g = p + 1; g <= b; ++g) gstart[g] = i;
    }
    if (i == n - 1) {
        for (int g = b + 1; g <= G; ++g) gstart[g] = n;
    }
}

// ---------------------------------------------------------------------------
// 5) fill CSR without atomics: pos = rowptr[dst] + rank
__global__ void fill_kernel(const int* __restrict__ src, const int* __restrict__ dst,
                            const float* __restrict__ w, const float* __restrict__ dinv,
                            const int* __restrict__ rowptr, const int* __restrict__ rank,
                            int2* __restrict__ csr, int E) {
    int e = blockIdx.x * blockDim.x + threadIdx.x;
    if (e >= E) return;
    int s = src[e], d = dst[e];
    float nv = dinv[s] * w[e] * dinv[d];
    csr[rowptr[d] + rank[e]] = make_int2(s, __float_as_int(nv));
}

// ---------------------------------------------------------------------------
// 6) layer 1: gather raw x (4 dims) + self-loop, h1 = relu(agg@W1+b1) -> bf16
__global__ void layer1_kernel(const float* __restrict__ x, const int* __restrict__ rowptr,
                              const int* __restrict__ count, const int2* __restrict__ csr,
                              const float* __restrict__ dinv, const float* __restrict__ W1,
                              const float* __restrict__ b1, unsigned* __restrict__ h1, int n) {
    __shared__ float sW[FIN * HID];
    __shared__ float sb[HID];
    int t = threadIdx.x;
    if (t < FIN * HID) sW[t] = W1[t];
    if (t < HID) sb[t] = b1[t];
    __syncthreads();
    int i = blockIdx.x * blockDim.x + t;
    if (i >= n) return;
    float di = dinv[i];
    float d2 = di * di;
    float4 a = *reinterpret_cast<const float4*>(x + (size_t)i * FIN);
    a.x *= d2; a.y *= d2; a.z *= d2; a.w *= d2;
    int beg = rowptr[i], c = count[i];
    for (int j = 0; j < c; ++j) {
        int2 rec = csr[beg + j];
        float nv = __int_as_float(rec.y);
        float4 xs = *reinterpret_cast<const float4*>(x + (size_t)rec.x * FIN);
        a.x += nv * xs.x; a.y += nv * xs.y; a.z += nv * xs.z; a.w += nv * xs.w;
    }
    unsigned* hp = h1 + (size_t)i * (HID / 2);
    #pragma unroll
    for (int k = 0; k < HID; k += 2) {
        float h0 = fmaxf(sb[k]   + a.x*sW[0*HID+k]   + a.y*sW[1*HID+k]   + a.z*sW[2*HID+k]   + a.w*sW[3*HID+k],   0.f);
        float h1v= fmaxf(sb[k+1] + a.x*sW[0*HID+k+1] + a.y*sW[1*HID+k+1] + a.z*sW[2*HID+k+1] + a.w*sW[3*HID+k+1], 0.f);
        hp[k / 2] = pack_bf16x2(h0, h1v);
    }
}

// ---------------------------------------------------------------------------
// 7) layer 2: bf16 gathers (4 lanes/node x 16B), W2 + relu, write h2 bf16
__global__ void layer2_kernel(const unsigned* __restrict__ h1, const int* __restrict__ rowptr,
                              const int* __restrict__ count, const int2* __restrict__ csr,
                              const float* __restrict__ dinv, const float* __restrict__ W2,
                              const float* __restrict__ b2, unsigned* __restrict__ h2, int n) {
    __shared__ float sW[HID * HID];
    __shared__ float sb[HID];
    __shared__ float sAgg[64][HID + 1];
    int t = threadIdx.x;
    for (int q = t; q < HID * HID; q += blockDim.x) sW[q] = W2[q];
    if (t < HID) sb[t] = b2[t];
    __syncthreads();
    int nib = t >> 2;          // node-in-block 0..63
    int l   = t & 3;           // 8-dim lane 0..3
    int i = blockIdx.x * 64 + nib;
    const uint4* h1q = reinterpret_cast<const uint4*>(h1);
    float acc[8];
    if (i < n) {
        float di = dinv[i];
        float d2 = di * di;
        uint4 hv = h1q[(size_t)i * 4 + l];
        unsigned hw[4] = {hv.x, hv.y, hv.z, hv.w};
        #pragma unroll
        for (int q = 0; q < 4; ++q) {
            acc[q*2]   = __uint_as_float(hw[q] << 16) * d2;
            acc[q*2+1] = __uint_as_float(hw[q] & 0xFFFF0000u) * d2;
        }
        int beg = rowptr[i], c = count[i];
        for (int j = 0; j < c; ++j) {
            int2 rec = csr[beg + j];
            float nv = __int_as_float(rec.y);
            uint4 hs = h1q[(size_t)rec.x * 4 + l];
            unsigned sw[4] = {hs.x, hs.y, hs.z, hs.w};
            #pragma unroll
            for (int q = 0; q < 4; ++q) {
                acc[q*2]   += nv * __uint_as_float(sw[q] << 16);
                acc[q*2+1] += nv * __uint_as_float(sw[q] & 0xFFFF0000u);
            }
        }
    } else {
        #pragma unroll
        for (int q = 0; q < 8; ++q) acc[q] = 0.f;
    }
    #pragma unroll
    for (int q = 0; q < 8; ++q) sAgg[nib][l * 8 + q] = acc[q];
    __syncthreads();
    if (i < n) {
        unsigned out[4];
        #pragma unroll
        for (int q = 0; q < 4; ++q) {
            int k0 = l * 8 + q * 2;
            float a0 = sb[k0], a1 = sb[k0 + 1];
            #pragma unroll
            for (int j = 0; j < HID; ++j) {
                float av = sAgg[nib][j];
                a0 += av * sW[j * HID + k0];
                a1 += av * sW[j * HID + k0 + 1];
            }
            out[q] = pack_bf16x2(fmaxf(a0, 0.f), fmaxf(a1, 0.f));
        }
        uint4* h2q = reinterpret_cast<uint4*>(h2);
        h2q[(size_t)i * 4 + l] = make_uint4(out[0], out[1], out[2], out[3]);
    }
}

// ---------------------------------------------------------------------------
// 8) fused mean-pool + heads: 32 lanes per graph, shuffle reduce
__global__ void poolheads_kernel(const unsigned* __restrict__ h2, const int* __restrict__ gstart,
                                 const float* __restrict__ Wo, const float* __restrict__ bo,
                                 const float* __restrict__ Wb, const float* __restrict__ bb,
                                 float* __restrict__ out, int G) {
    int g = blockIdx.x * 8 + (threadIdx.x >> 5);
    int k = threadIdx.x & 31;
    if (g >= G) return;
    int s0 = gstart[g], s1 = gstart[g + 1];
    float sum = 0.f;
    const unsigned short* h2s = reinterpret_cast<const unsigned short*>(h2);
    for (int i = s0; i < s1; ++i) {
        unsigned u = (unsigned)h2s[(size_t)i * HID + k] << 16;
        sum += __uint_as_float(u);
    }
    float cnt = (float)(s1 - s0);
    float inv = 1.0f / fmaxf(cnt, 1.0f);
    float m = sum * inv;
    float po = m * Wo[k];
    float pb = m * Wb[k];
    #pragma unroll
    for (int off = 16; off >= 1; off >>= 1) {
        po += __shfl_xor(po, off);
        pb += __shfl_xor(pb, off);
    }
    if (k == 0) {
        out[g]     = 1.0f / (1.0f + expf(-(po + bo[0])));
        out[G + g] = 1.0f / (1.0f + expf(-(pb + bb[0])));
    }
}

// ---------------------------------------------------------------------------
extern "C" void kernel_launch(void* const* d_in, const int* in_sizes, int n_in,
                              void* d_out, int out_size, void* d_ws, size_t ws_size,
                              hipStream_t stream) {
    const float* x     = (const float*)d_in[0];
    const int*   ei    = (const int*)d_in[1];
    const float* ew    = (const float*)d_in[2];
    const int*   batch = (const int*)d_in[3];
    const float* W1 = (const float*)d_in[5];
    const float* b1 = (const float*)d_in[6];
    const float* W2 = (const float*)d_in[7];
    const float* b2 = (const float*)d_in[8];
    const float* Wo = (const float*)d_in[9];
    const float* bo = (const float*)d_in[10];
    const float* Wb = (const float*)d_in[11];
    const float* bb = (const float*)d_in[12];
    float* out = (float*)d_out;

    const int n = in_sizes[0] / FIN;   // 100000
    const int E = in_sizes[2];         // 1600000
    const int G = out_size / 2;        // 16384
    const int* src = ei;
    const int* dst = ei + E;
    const int n4 = (n + 3) & ~3;
    const int nb = (n + SCAN_B - 1) / SCAN_B;
    const int nbp = (nb + 511) & ~511;

    // workspace layout (all regions 16B-aligned)
    char* wsb = (char*)d_ws;
    int2*     csr    = (int2*)wsb;                              // E * 8B
    unsigned long long* packed = (unsigned long long*)(wsb + (size_t)E * 8);  // n4 * 8B
    int*      rank   = (int*)(packed + n4);                     // E * 4B
    int*      counti = rank + E;                                // n4
    float*    dinv   = (float*)(counti + n4);                   // n4
    int*      rowptr = (int*)(dinv + n4);                       // n4
    int*      bscan  = rowptr + n4;                             // n4
    int*      bsum   = bscan + n4;                              // nbp
    int*      gstart = bsum + nbp;                              // G+16
    unsigned* h1     = (unsigned*)(gstart + G + 16);            // n * 16 (bf16x32)
    unsigned* h2     = h1 + (size_t)n4 * (HID / 2);             // n * 16

    hipMemsetAsync(packed, 0, (size_t)n4 * 8, stream);

    const int B = 256;
    hist_kernel  <<<(E + B - 1) / B, B, 0, stream>>>(dst, ew, packed, rank, E);
    dinv_kernel  <<<(n + B - 1) / B, B, 0, stream>>>(packed, dinv, counti, n);
    scan1_kernel <<<nb, SCAN_B, 0, stream>>>(counti, bscan, bsum, n);
    scan2_kernel <<<1, 512, 0, stream>>>(bsum, nb);
    scan3_kernel <<<nb, SCAN_B, 0, stream>>>(bscan, counti, bsum, rowptr, n);
    bounds_kernel<<<(n + B - 1) / B, B, 0, stream>>>(batch, gstart, n, G);
    fill_kernel  <<<(E + B - 1) / B, B, 0, stream>>>(src, dst, ew, dinv, rowptr, rank, csr, E);
    layer1_kernel<<<(n + B - 1) / B, B, 0, stream>>>(x, rowptr, counti, csr, dinv, W1, b1, h1, n);
    layer2_kernel<<<(n + 63) / 64, B, 0, stream>>>(h1, rowptr, counti, csr, dinv, W2, b2, h2, n);
    poolheads_kernel<<<(G + 7) / 8, B, 0, stream>>>(h2, gstart, Wo, bo, Wb, bb, out, G);
}

// Round 4
// 193.997 us; speedup vs baseline: 5.8032x; 1.0225x over previous
//
#include <hip/hip_runtime.h>
#include <math.h>

#define FIN 4
#define HID 32
#define SCAN_B 256

__device__ __forceinline__ unsigned pack_bf16x2(float a, float b) {
    unsigned ua = __float_as_uint(a); ua += 0x7FFF + ((ua >> 16) & 1);
    unsigned ub = __float_as_uint(b); ub += 0x7FFF + ((ub >> 16) & 1);
    return (ua >> 16) | (ub & 0xFFFF0000u);
}

// ---------------------------------------------------------------------------
// 1) count-only histogram: u32 atomic; return value = edge's rank in its bucket
__global__ void hist_kernel(const int* __restrict__ dst, unsigned* __restrict__ count,
                            int* __restrict__ rank, int E) {
    int e = blockIdx.x * blockDim.x + threadIdx.x;
    if (e >= E) return;
    rank[e] = (int)atomicAdd(&count[dst[e]], 1u);
}

// ---------------------------------------------------------------------------
// 2) scans for rowptr (exclusive prefix of count)
__global__ void scan1_kernel(const int* __restrict__ count, int* __restrict__ bscan,
                             int* __restrict__ bsum, int n) {
    __shared__ int s[SCAN_B];
    int i = blockIdx.x * SCAN_B + threadIdx.x;
    int v = (i < n) ? count[i] : 0;
    s[threadIdx.x] = v;
    __syncthreads();
    for (int off = 1; off < SCAN_B; off <<= 1) {
        int t = (threadIdx.x >= off) ? s[threadIdx.x - off] : 0;
        __syncthreads();
        s[threadIdx.x] += t;
        __syncthreads();
    }
    if (i < n) bscan[i] = s[threadIdx.x];
    if (threadIdx.x == SCAN_B - 1) bsum[blockIdx.x] = s[threadIdx.x];
}

__global__ void scan2_kernel(int* __restrict__ data, int nb) {
    __shared__ int s[512];
    __shared__ int carry;
    if (threadIdx.x == 0) carry = 0;
    __syncthreads();
    for (int base = 0; base < nb; base += 512) {
        int idx = base + threadIdx.x;
        int v = (idx < nb) ? data[idx] : 0;
        s[threadIdx.x] = v;
        __syncthreads();
        for (int off = 1; off < 512; off <<= 1) {
            int t = (threadIdx.x >= off) ? s[threadIdx.x - off] : 0;
            __syncthreads();
            s[threadIdx.x] += t;
            __syncthreads();
        }
        int incl = s[threadIdx.x] + carry;
        if (idx < nb) data[idx] = incl;
        __syncthreads();
        if (threadIdx.x == 511) carry = incl;
        __syncthreads();
    }
}

__global__ void scan3_kernel(const int* __restrict__ bscan, const int* __restrict__ count,
                             const int* __restrict__ bsumscan, int* __restrict__ rowptr, int n) {
    int i = blockIdx.x * SCAN_B + threadIdx.x;
    if (i >= n) return;
    int off = (blockIdx.x == 0) ? 0 : bsumscan[blockIdx.x - 1];
    rowptr[i] = bscan[i] - count[i] + off;
}

// ---------------------------------------------------------------------------
// 3) graph segment boundaries from sorted batch
__global__ void bounds_kernel(const int* __restrict__ batch, int* __restrict__ gstart,
                              int n, int G) {
    int i = blockIdx.x * blockDim.x + threadIdx.x;
    if (i >= n) return;
    int b = batch[i];
    if (i == 0) {
        for (int g = 0; g <= b; ++g) gstart[g] = 0;
    } else {
        int p = batch[i - 1];
        for (int g = p + 1; g <= b; ++g) gstart[g] = i;
    }
    if (i == n - 1) {
        for (int g = b + 1; g <= G; ++g) gstart[g] = n;
    }
}

// ---------------------------------------------------------------------------
// 4) fill CSR without atomics: csr[rowptr[dst]+rank] = (src, raw_w)
__global__ void fill_kernel(const int* __restrict__ src, const int* __restrict__ dst,
                            const float* __restrict__ w, const int* __restrict__ rowptr,
                            const int* __restrict__ rank, int2* __restrict__ csr, int E) {
    int e = blockIdx.x * blockDim.x + threadIdx.x;
    if (e >= E) return;
    int d = dst[e];
    csr[rowptr[d] + rank[e]] = make_int2(src[e], __float_as_int(w[e]));
}

// ---------------------------------------------------------------------------
// 5) weighted degree from CSR buckets (no atomics) -> dinv
__global__ void wdeg_dinv_kernel(const int* __restrict__ rowptr, const int* __restrict__ count,
                                 const int2* __restrict__ csr, float* __restrict__ dinv, int n) {
    int i = blockIdx.x * blockDim.x + threadIdx.x;
    if (i >= n) return;
    int beg = rowptr[i], c = count[i];
    float s = 0.f;
    for (int j = 0; j < c; ++j) s += __int_as_float(csr[beg + j].y);
    dinv[i] = rsqrtf(s + 1.0f);
}

// ---------------------------------------------------------------------------
// 6) layer 1: compute norm in-flight (write back to csr.y for layer2),
//    gather raw x (4 dims) + self-loop, h1 = relu(agg@W1+b1) -> bf16
__global__ void layer1_kernel(const float* __restrict__ x, const int* __restrict__ rowptr,
                              const int* __restrict__ count, int2* __restrict__ csr,
                              const float* __restrict__ dinv, const float* __restrict__ W1,
                              const float* __restrict__ b1, unsigned* __restrict__ h1, int n) {
    __shared__ float sW[FIN * HID];
    __shared__ float sb[HID];
    int t = threadIdx.x;
    if (t < FIN * HID) sW[t] = W1[t];
    if (t < HID) sb[t] = b1[t];
    __syncthreads();
    int i = blockIdx.x * blockDim.x + t;
    if (i >= n) return;
    float di = dinv[i];
    float d2 = di * di;
    float4 a = *reinterpret_cast<const float4*>(x + (size_t)i * FIN);
    a.x *= d2; a.y *= d2; a.z *= d2; a.w *= d2;
    int beg = rowptr[i], c = count[i];
    for (int j = 0; j < c; ++j) {
        int2 rec = csr[beg + j];
        float nv = dinv[rec.x] * __int_as_float(rec.y) * di;
        csr[beg + j].y = __float_as_int(nv);          // persist norm for layer2
        float4 xs = *reinterpret_cast<const float4*>(x + (size_t)rec.x * FIN);
        a.x += nv * xs.x; a.y += nv * xs.y; a.z += nv * xs.z; a.w += nv * xs.w;
    }
    unsigned* hp = h1 + (size_t)i * (HID / 2);
    #pragma unroll
    for (int k = 0; k < HID; k += 2) {
        float h0 = fmaxf(sb[k]   + a.x*sW[0*HID+k]   + a.y*sW[1*HID+k]   + a.z*sW[2*HID+k]   + a.w*sW[3*HID+k],   0.f);
        float h1v= fmaxf(sb[k+1] + a.x*sW[0*HID+k+1] + a.y*sW[1*HID+k+1] + a.z*sW[2*HID+k+1] + a.w*sW[3*HID+k+1], 0.f);
        hp[k / 2] = pack_bf16x2(h0, h1v);
    }
}

// ---------------------------------------------------------------------------
// 7) layer 2: bf16 gathers (4 lanes/node x 16B), unrolled x2, W2 + relu -> h2 bf16
__global__ void layer2_kernel(const unsigned* __restrict__ h1, const int* __restrict__ rowptr,
                              const int* __restrict__ count, const int2* __restrict__ csr,
                              const float* __restrict__ dinv, const float* __restrict__ W2,
                              const float* __restrict__ b2, unsigned* __restrict__ h2, int n) {
    __shared__ float sW[HID * HID];
    __shared__ float sb[HID];
    __shared__ float sAgg[64][HID + 1];
    int t = threadIdx.x;
    for (int q = t; q < HID * HID; q += blockDim.x) sW[q] = W2[q];
    if (t < HID) sb[t] = b2[t];
    __syncthreads();
    int nib = t >> 2;          // node-in-block 0..63
    int l   = t & 3;           // 8-dim lane 0..3
    int i = blockIdx.x * 64 + nib;
    const uint4* h1q = reinterpret_cast<const uint4*>(h1);
    float acc[8];
    if (i < n) {
        float di = dinv[i];
        float d2 = di * di;
        uint4 hv = h1q[(size_t)i * 4 + l];
        unsigned hw[4] = {hv.x, hv.y, hv.z, hv.w};
        #pragma unroll
        for (int q = 0; q < 4; ++q) {
            acc[q*2]   = __uint_as_float(hw[q] << 16) * d2;
            acc[q*2+1] = __uint_as_float(hw[q] & 0xFFFF0000u) * d2;
        }
        int beg = rowptr[i], c = count[i];
        int j = 0;
        for (; j + 1 < c; j += 2) {
            int2 r0 = csr[beg + j];
            int2 r1 = csr[beg + j + 1];
            float n0 = __int_as_float(r0.y);
            float n1 = __int_as_float(r1.y);
            uint4 s0 = h1q[(size_t)r0.x * 4 + l];
            uint4 s1 = h1q[(size_t)r1.x * 4 + l];
            unsigned w0[4] = {s0.x, s0.y, s0.z, s0.w};
            unsigned w1[4] = {s1.x, s1.y, s1.z, s1.w};
            #pragma unroll
            for (int q = 0; q < 4; ++q) {
                acc[q*2]   += n0 * __uint_as_float(w0[q] << 16);
                acc[q*2+1] += n0 * __uint_as_float(w0[q] & 0xFFFF0000u);
                acc[q*2]   += n1 * __uint_as_float(w1[q] << 16);
                acc[q*2+1] += n1 * __uint_as_float(w1[q] & 0xFFFF0000u);
            }
        }
        if (j < c) {
            int2 r0 = csr[beg + j];
            float n0 = __int_as_float(r0.y);
            uint4 s0 = h1q[(size_t)r0.x * 4 + l];
            unsigned w0[4] = {s0.x, s0.y, s0.z, s0.w};
            #pragma unroll
            for (int q = 0; q < 4; ++q) {
                acc[q*2]   += n0 * __uint_as_float(w0[q] << 16);
                acc[q*2+1] += n0 * __uint_as_float(w0[q] & 0xFFFF0000u);
            }
        }
    } else {
        #pragma unroll
        for (int q = 0; q < 8; ++q) acc[q] = 0.f;
    }
    #pragma unroll
    for (int q = 0; q < 8; ++q) sAgg[nib][l * 8 + q] = acc[q];
    __syncthreads();
    if (i < n) {
        unsigned outp[4];
        #pragma unroll
        for (int q = 0; q < 4; ++q) {
            int k0 = l * 8 + q * 2;
            float a0 = sb[k0], a1 = sb[k0 + 1];
            #pragma unroll
            for (int j = 0; j < HID; ++j) {
                float av = sAgg[nib][j];
                a0 += av * sW[j * HID + k0];
                a1 += av * sW[j * HID + k0 + 1];
            }
            outp[q] = pack_bf16x2(fmaxf(a0, 0.f), fmaxf(a1, 0.f));
        }
        uint4* h2q = reinterpret_cast<uint4*>(h2);
        h2q[(size_t)i * 4 + l] = make_uint4(outp[0], outp[1], outp[2], outp[3]);
    }
}

// ---------------------------------------------------------------------------
// 8) fused mean-pool + heads: 32 lanes per graph, shuffle reduce
__global__ void poolheads_kernel(const unsigned* __restrict__ h2, const int* __restrict__ gstart,
                                 const float* __restrict__ Wo, const float* __restrict__ bo,
                                 const float* __restrict__ Wb, const float* __restrict__ bb,
                                 float* __restrict__ out, int G) {
    int g = blockIdx.x * 8 + (threadIdx.x >> 5);
    int k = threadIdx.x & 31;
    if (g >= G) return;
    int s0 = gstart[g], s1 = gstart[g + 1];
    float sum = 0.f;
    const unsigned short* h2s = reinterpret_cast<const unsigned short*>(h2);
    for (int i = s0; i < s1; ++i) {
        unsigned u = (unsigned)h2s[(size_t)i * HID + k] << 16;
        sum += __uint_as_float(u);
    }
    float cnt = (float)(s1 - s0);
    float inv = 1.0f / fmaxf(cnt, 1.0f);
    float m = sum * inv;
    float po = m * Wo[k];
    float pb = m * Wb[k];
    #pragma unroll
    for (int off = 16; off >= 1; off >>= 1) {
        po += __shfl_xor(po, off);
        pb += __shfl_xor(pb, off);
    }
    if (k == 0) {
        out[g]     = 1.0f / (1.0f + expf(-(po + bo[0])));
        out[G + g] = 1.0f / (1.0f + expf(-(pb + bb[0])));
    }
}

// ---------------------------------------------------------------------------
extern "C" void kernel_launch(void* const* d_in, const int* in_sizes, int n_in,
                              void* d_out, int out_size, void* d_ws, size_t ws_size,
                              hipStream_t stream) {
    const float* x     = (const float*)d_in[0];
    const int*   ei    = (const int*)d_in[1];
    const float* ew    = (const float*)d_in[2];
    const int*   batch = (const int*)d_in[3];
    const float* W1 = (const float*)d_in[5];
    const float* b1 = (const float*)d_in[6];
    const float* W2 = (const float*)d_in[7];
    const float* b2 = (const float*)d_in[8];
    const float* Wo = (const float*)d_in[9];
    const float* bo = (const float*)d_in[10];
    const float* Wb = (const float*)d_in[11];
    const float* bb = (const float*)d_in[12];
    float* out = (float*)d_out;

    const int n = in_sizes[0] / FIN;   // 100000
    const int E = in_sizes[2];         // 1600000
    const int G = out_size / 2;        // 16384
    const int* src = ei;
    const int* dst = ei + E;
    const int n4 = (n + 3) & ~3;
    const int nb = (n + SCAN_B - 1) / SCAN_B;
    const int nbp = (nb + 511) & ~511;

    // workspace layout (all regions 16B-aligned)
    char* wsb = (char*)d_ws;
    int2*     csr    = (int2*)wsb;                          // E * 8B
    unsigned* count  = (unsigned*)(wsb + (size_t)E * 8);    // n4  (zeroed)
    int*      rank   = (int*)(count + n4);                  // E
    float*    dinv   = (float*)(rank + E);                  // n4
    int*      rowptr = (int*)(dinv + n4);                   // n4
    int*      bscan  = rowptr + n4;                         // n4
    int*      bsum   = bscan + n4;                          // nbp
    int*      gstart = bsum + nbp;                          // G+16
    unsigned* h1     = (unsigned*)(gstart + G + 16);        // n4 * 16B (bf16x32)
    unsigned* h2     = h1 + (size_t)n4 * (HID / 2);         // n4 * 16B

    hipMemsetAsync(count, 0, (size_t)n4 * 4, stream);

    const int B = 256;
    hist_kernel    <<<(E + B - 1) / B, B, 0, stream>>>(dst, count, rank, E);
    scan1_kernel   <<<nb, SCAN_B, 0, stream>>>((const int*)count, bscan, bsum, n);
    scan2_kernel   <<<1, 512, 0, stream>>>(bsum, nb);
    scan3_kernel   <<<nb, SCAN_B, 0, stream>>>(bscan, (const int*)count, bsum, rowptr, n);
    bounds_kernel  <<<(n + B - 1) / B, B, 0, stream>>>(batch, gstart, n, G);
    fill_kernel    <<<(E + B - 1) / B, B, 0, stream>>>(src, dst, ew, rowptr, rank, csr, E);
    wdeg_dinv_kernel<<<(n + B - 1) / B, B, 0, stream>>>(rowptr, (const int*)count, csr, dinv, n);
    layer1_kernel  <<<(n + B - 1) / B, B, 0, stream>>>(x, rowptr, (const int*)count, csr, dinv, W1, b1, h1, n);
    layer2_kernel  <<<(n + 63) / 64, B, 0, stream>>>(h1, rowptr, (const int*)count, csr, dinv, W2, b2, h2, n);
    poolheads_kernel<<<(G + 7) / 8, B, 0, stream>>>(h2, gstart, Wo, bo, Wb, bb, out, G);
}

// Round 5
// 148.838 us; speedup vs baseline: 7.5640x; 1.3034x over previous
//
#include <hip/hip_runtime.h>
#include <math.h>

#define FIN 4
#define HID 32
#define SCAN_B 256
#define EPB 4096        // edges per binning block
#define BUCK_SH 9
#define BUCK_W 512      // nodes per bucket

__device__ __forceinline__ unsigned pack_bf16x2(float a, float b) {
    unsigned ua = __float_as_uint(a); ua += 0x7FFF + ((ua >> 16) & 1);
    unsigned ub = __float_as_uint(b); ub += 0x7FFF + ((ub >> 16) & 1);
    return (ua >> 16) | (ub & 0xFFFF0000u);
}

// ---------------------------------------------------------------------------
// 1a) per-block histogram over coarse buckets (LDS only, no global atomics)
__global__ void p1a_count(const int* __restrict__ dst, int* __restrict__ counts,
                          int E, int nbuck, int nblk) {
    __shared__ int h[256];
    int t = threadIdx.x;
    h[t] = 0;
    __syncthreads();
    int base = blockIdx.x * EPB;
    for (int k = t; k < EPB; k += 256) {
        int e = base + k;
        if (e < E) atomicAdd(&h[dst[e] >> BUCK_SH], 1);
    }
    __syncthreads();
    if (t < nbuck) counts[t * nblk + blockIdx.x] = h[t];
}

// ---------------------------------------------------------------------------
// scans (exclusive prefix over counts -> offsets)
__global__ void scan1_kernel(const int* __restrict__ count, int* __restrict__ bscan,
                             int* __restrict__ bsum, int n) {
    __shared__ int s[SCAN_B];
    int i = blockIdx.x * SCAN_B + threadIdx.x;
    int v = (i < n) ? count[i] : 0;
    s[threadIdx.x] = v;
    __syncthreads();
    for (int off = 1; off < SCAN_B; off <<= 1) {
        int t = (threadIdx.x >= off) ? s[threadIdx.x - off] : 0;
        __syncthreads();
        s[threadIdx.x] += t;
        __syncthreads();
    }
    if (i < n) bscan[i] = s[threadIdx.x];
    if (threadIdx.x == SCAN_B - 1) bsum[blockIdx.x] = s[threadIdx.x];
}

__global__ void scan2_kernel(int* __restrict__ data, int nb) {
    __shared__ int s[512];
    __shared__ int carry;
    if (threadIdx.x == 0) carry = 0;
    __syncthreads();
    for (int base = 0; base < nb; base += 512) {
        int idx = base + threadIdx.x;
        int v = (idx < nb) ? data[idx] : 0;
        s[threadIdx.x] = v;
        __syncthreads();
        for (int off = 1; off < 512; off <<= 1) {
            int t = (threadIdx.x >= off) ? s[threadIdx.x - off] : 0;
            __syncthreads();
            s[threadIdx.x] += t;
            __syncthreads();
        }
        int incl = s[threadIdx.x] + carry;
        if (idx < nb) data[idx] = incl;
        __syncthreads();
        if (threadIdx.x == 511) carry = incl;
        __syncthreads();
    }
}

__global__ void scan3_kernel(const int* __restrict__ bscan, const int* __restrict__ count,
                             const int* __restrict__ bsumscan, int* __restrict__ offsets, int n) {
    int i = blockIdx.x * SCAN_B + threadIdx.x;
    if (i >= n) return;
    int off = (blockIdx.x == 0) ? 0 : bsumscan[blockIdx.x - 1];
    offsets[i] = bscan[i] - count[i] + off;
}

// ---------------------------------------------------------------------------
// 1c) scatter edges into per-(bucket,block) regions via LDS cursors
__global__ void p1c_scatter(const int* __restrict__ src, const int* __restrict__ dst,
                            const float* __restrict__ w, const int* __restrict__ offsets,
                            unsigned long long* __restrict__ bkt, int E, int nbuck, int nblk) {
    __shared__ int cur[256];
    int t = threadIdx.x;
    if (t < nbuck) cur[t] = offsets[t * nblk + blockIdx.x];
    __syncthreads();
    int base = blockIdx.x * EPB;
    for (int k = t; k < EPB; k += 256) {
        int e = base + k;
        if (e < E) {
            int d = dst[e];
            int b = d >> BUCK_SH;
            int pos = atomicAdd(&cur[b], 1);
            unsigned hi = ((unsigned)(d & (BUCK_W - 1)) << 17) | (unsigned)src[e];
            bkt[pos] = ((unsigned long long)hi << 32) | (unsigned)__float_as_int(w[e]);
        }
    }
}

// ---------------------------------------------------------------------------
// 2) bucket -> final CSR: LDS node-histogram + scan + cursor scatter; also
//    accumulates weighted degree in LDS -> dinv.  One block per bucket.
__global__ void p2_csr(const unsigned long long* __restrict__ bkt, const int* __restrict__ offsets,
                       int2* __restrict__ csr, int* __restrict__ rowptr, int* __restrict__ count,
                       float* __restrict__ dinv, int E, int n, int nbuck, int nblk) {
    __shared__ int lcnt[BUCK_W];
    __shared__ int s[BUCK_W];
    __shared__ int curL[BUCK_W];
    __shared__ float wsum[BUCK_W];
    int b = blockIdx.x;
    int t = threadIdx.x;   // 512 threads
    int base = offsets[b * nblk];
    int end  = (b == nbuck - 1) ? E : offsets[(b + 1) * nblk];
    int cnt  = end - base;
    lcnt[t] = 0;
    wsum[t] = 0.f;
    __syncthreads();
    for (int k = t; k < cnt; k += BUCK_W) {
        unsigned hi = (unsigned)(bkt[base + k] >> 32);
        atomicAdd(&lcnt[hi >> 17], 1);
    }
    __syncthreads();
    s[t] = lcnt[t];
    __syncthreads();
    for (int off = 1; off < BUCK_W; off <<= 1) {
        int v = (t >= off) ? s[t - off] : 0;
        __syncthreads();
        s[t] += v;
        __syncthreads();
    }
    int excl = s[t] - lcnt[t];
    curL[t] = excl;
    int node = (b << BUCK_SH) + t;
    if (node < n) { rowptr[node] = base + excl; count[node] = lcnt[t]; }
    __syncthreads();
    for (int k = t; k < cnt; k += BUCK_W) {
        unsigned long long v = bkt[base + k];
        unsigned hi = (unsigned)(v >> 32);
        int ld = hi >> 17;
        int sN = hi & 0x1FFFF;
        float wv = __int_as_float((int)(unsigned)v);
        int p = atomicAdd(&curL[ld], 1);
        csr[base + p] = make_int2(sN, __float_as_int(wv));
        atomicAdd(&wsum[ld], wv);
    }
    __syncthreads();
    if (node < n) dinv[node] = rsqrtf(wsum[t] + 1.0f);
}

// ---------------------------------------------------------------------------
// graph segment boundaries from sorted batch
__global__ void bounds_kernel(const int* __restrict__ batch, int* __restrict__ gstart,
                              int n, int G) {
    int i = blockIdx.x * blockDim.x + threadIdx.x;
    if (i >= n) return;
    int b = batch[i];
    if (i == 0) {
        for (int g = 0; g <= b; ++g) gstart[g] = 0;
    } else {
        int p = batch[i - 1];
        for (int g = p + 1; g <= b; ++g) gstart[g] = i;
    }
    if (i == n - 1) {
        for (int g = b + 1; g <= G; ++g) gstart[g] = n;
    }
}

// ---------------------------------------------------------------------------
// layer 1: compute norm in-flight (write back to csr.y for layer2),
// gather raw x (4 dims) + self-loop, h1 = relu(agg@W1+b1) -> bf16
__global__ void layer1_kernel(const float* __restrict__ x, const int* __restrict__ rowptr,
                              const int* __restrict__ count, int2* __restrict__ csr,
                              const float* __restrict__ dinv, const float* __restrict__ W1,
                              const float* __restrict__ b1, unsigned* __restrict__ h1, int n) {
    __shared__ float sW[FIN * HID];
    __shared__ float sb[HID];
    int t = threadIdx.x;
    if (t < FIN * HID) sW[t] = W1[t];
    if (t < HID) sb[t] = b1[t];
    __syncthreads();
    int i = blockIdx.x * blockDim.x + t;
    if (i >= n) return;
    float di = dinv[i];
    float d2 = di * di;
    float4 a = *reinterpret_cast<const float4*>(x + (size_t)i * FIN);
    a.x *= d2; a.y *= d2; a.z *= d2; a.w *= d2;
    int beg = rowptr[i], c = count[i];
    for (int j = 0; j < c; ++j) {
        int2 rec = csr[beg + j];
        float nv = dinv[rec.x] * __int_as_float(rec.y) * di;
        csr[beg + j].y = __float_as_int(nv);          // persist norm for layer2
        float4 xs = *reinterpret_cast<const float4*>(x + (size_t)rec.x * FIN);
        a.x += nv * xs.x; a.y += nv * xs.y; a.z += nv * xs.z; a.w += nv * xs.w;
    }
    unsigned* hp = h1 + (size_t)i * (HID / 2);
    #pragma unroll
    for (int k = 0; k < HID; k += 2) {
        float h0 = fmaxf(sb[k]   + a.x*sW[0*HID+k]   + a.y*sW[1*HID+k]   + a.z*sW[2*HID+k]   + a.w*sW[3*HID+k],   0.f);
        float h1v= fmaxf(sb[k+1] + a.x*sW[0*HID+k+1] + a.y*sW[1*HID+k+1] + a.z*sW[2*HID+k+1] + a.w*sW[3*HID+k+1], 0.f);
        hp[k / 2] = pack_bf16x2(h0, h1v);
    }
}

// ---------------------------------------------------------------------------
// layer 2: bf16 gathers (4 lanes/node x 16B), unrolled x2, W2 + relu -> h2 bf16
__global__ void layer2_kernel(const unsigned* __restrict__ h1, const int* __restrict__ rowptr,
                              const int* __restrict__ count, const int2* __restrict__ csr,
                              const float* __restrict__ dinv, const float* __restrict__ W2,
                              const float* __restrict__ b2, unsigned* __restrict__ h2, int n) {
    __shared__ float sW[HID * HID];
    __shared__ float sb[HID];
    __shared__ float sAgg[64][HID + 1];
    int t = threadIdx.x;
    for (int q = t; q < HID * HID; q += blockDim.x) sW[q] = W2[q];
    if (t < HID) sb[t] = b2[t];
    __syncthreads();
    int nib = t >> 2;          // node-in-block 0..63
    int l   = t & 3;           // 8-dim lane 0..3
    int i = blockIdx.x * 64 + nib;
    const uint4* h1q = reinterpret_cast<const uint4*>(h1);
    float acc[8];
    if (i < n) {
        float di = dinv[i];
        float d2 = di * di;
        uint4 hv = h1q[(size_t)i * 4 + l];
        unsigned hw[4] = {hv.x, hv.y, hv.z, hv.w};
        #pragma unroll
        for (int q = 0; q < 4; ++q) {
            acc[q*2]   = __uint_as_float(hw[q] << 16) * d2;
            acc[q*2+1] = __uint_as_float(hw[q] & 0xFFFF0000u) * d2;
        }
        int beg = rowptr[i], c = count[i];
        int j = 0;
        for (; j + 1 < c; j += 2) {
            int2 r0 = csr[beg + j];
            int2 r1 = csr[beg + j + 1];
            float n0 = __int_as_float(r0.y);
            float n1 = __int_as_float(r1.y);
            uint4 s0 = h1q[(size_t)r0.x * 4 + l];
            uint4 s1 = h1q[(size_t)r1.x * 4 + l];
            unsigned w0[4] = {s0.x, s0.y, s0.z, s0.w};
            unsigned w1[4] = {s1.x, s1.y, s1.z, s1.w};
            #pragma unroll
            for (int q = 0; q < 4; ++q) {
                acc[q*2]   += n0 * __uint_as_float(w0[q] << 16);
                acc[q*2+1] += n0 * __uint_as_float(w0[q] & 0xFFFF0000u);
                acc[q*2]   += n1 * __uint_as_float(w1[q] << 16);
                acc[q*2+1] += n1 * __uint_as_float(w1[q] & 0xFFFF0000u);
            }
        }
        if (j < c) {
            int2 r0 = csr[beg + j];
            float n0 = __int_as_float(r0.y);
            uint4 s0 = h1q[(size_t)r0.x * 4 + l];
            unsigned w0[4] = {s0.x, s0.y, s0.z, s0.w};
            #pragma unroll
            for (int q = 0; q < 4; ++q) {
                acc[q*2]   += n0 * __uint_as_float(w0[q] << 16);
                acc[q*2+1] += n0 * __uint_as_float(w0[q] & 0xFFFF0000u);
            }
        }
    } else {
        #pragma unroll
        for (int q = 0; q < 8; ++q) acc[q] = 0.f;
    }
    #pragma unroll
    for (int q = 0; q < 8; ++q) sAgg[nib][l * 8 + q] = acc[q];
    __syncthreads();
    if (i < n) {
        unsigned outp[4];
        #pragma unroll
        for (int q = 0; q < 4; ++q) {
            int k0 = l * 8 + q * 2;
            float a0 = sb[k0], a1 = sb[k0 + 1];
            #pragma unroll
            for (int j = 0; j < HID; ++j) {
                float av = sAgg[nib][j];
                a0 += av * sW[j * HID + k0];
                a1 += av * sW[j * HID + k0 + 1];
            }
            outp[q] = pack_bf16x2(fmaxf(a0, 0.f), fmaxf(a1, 0.f));
        }
        uint4* h2q = reinterpret_cast<uint4*>(h2);
        h2q[(size_t)i * 4 + l] = make_uint4(outp[0], outp[1], outp[2], outp[3]);
    }
}

// ---------------------------------------------------------------------------
// fused mean-pool + heads: 32 lanes per graph, shuffle reduce
__global__ void poolheads_kernel(const unsigned* __restrict__ h2, const int* __restrict__ gstart,
                                 const float* __restrict__ Wo, const float* __restrict__ bo,
                                 const float* __restrict__ Wb, const float* __restrict__ bb,
                                 float* __restrict__ out, int G) {
    int g = blockIdx.x * 8 + (threadIdx.x >> 5);
    int k = threadIdx.x & 31;
    if (g >= G) return;
    int s0 = gstart[g], s1 = gstart[g + 1];
    float sum = 0.f;
    const unsigned short* h2s = reinterpret_cast<const unsigned short*>(h2);
    for (int i = s0; i < s1; ++i) {
        unsigned u = (unsigned)h2s[(size_t)i * HID + k] << 16;
        sum += __uint_as_float(u);
    }
    float cnt = (float)(s1 - s0);
    float inv = 1.0f / fmaxf(cnt, 1.0f);
    float m = sum * inv;
    float po = m * Wo[k];
    float pb = m * Wb[k];
    #pragma unroll
    for (int off = 16; off >= 1; off >>= 1) {
        po += __shfl_xor(po, off);
        pb += __shfl_xor(pb, off);
    }
    if (k == 0) {
        out[g]     = 1.0f / (1.0f + expf(-(po + bo[0])));
        out[G + g] = 1.0f / (1.0f + expf(-(pb + bb[0])));
    }
}

// ---------------------------------------------------------------------------
extern "C" void kernel_launch(void* const* d_in, const int* in_sizes, int n_in,
                              void* d_out, int out_size, void* d_ws, size_t ws_size,
                              hipStream_t stream) {
    const float* x     = (const float*)d_in[0];
    const int*   ei    = (const int*)d_in[1];
    const float* ew    = (const float*)d_in[2];
    const int*   batch = (const int*)d_in[3];
    const float* W1 = (const float*)d_in[5];
    const float* b1 = (const float*)d_in[6];
    const float* W2 = (const float*)d_in[7];
    const float* b2 = (const float*)d_in[8];
    const float* Wo = (const float*)d_in[9];
    const float* bo = (const float*)d_in[10];
    const float* Wb = (const float*)d_in[11];
    const float* bb = (const float*)d_in[12];
    float* out = (float*)d_out;

    const int n = in_sizes[0] / FIN;   // 100000
    const int E = in_sizes[2];         // 1600000
    const int G = out_size / 2;        // 16384
    const int* src = ei;
    const int* dst = ei + E;
    const int n4 = (n + 3) & ~3;
    const int nblk  = (E + EPB - 1) / EPB;          // binning blocks (391)
    const int nbuck = (n + BUCK_W - 1) / BUCK_W;    // coarse buckets (196)
    const int M  = nbuck * nblk;                    // (bucket,block) counts
    const int Mp = (M + 3) & ~3;
    const int nbM = (M + SCAN_B - 1) / SCAN_B;
    const int nbp = (nbM + 511) & ~511;

    // workspace layout (all regions 16B-aligned)
    char* wsb = (char*)d_ws;
    unsigned long long* bkt = (unsigned long long*)wsb;       // E * 8B
    int2*     csr     = (int2*)(wsb + (size_t)E * 8);         // E * 8B
    int*      counts  = (int*)(wsb + (size_t)E * 16);         // Mp
    int*      offsets = counts + Mp;                          // Mp
    int*      bscan   = offsets + Mp;                         // Mp
    int*      bsum    = bscan + Mp;                           // nbp
    int*      rowptr  = bsum + nbp;                           // n4
    int*      count   = rowptr + n4;                          // n4
    float*    dinv    = (float*)(count + n4);                 // n4
    int*      gstart  = (int*)(dinv + n4);                    // G+16
    unsigned* h1      = (unsigned*)(gstart + G + 16);         // n4 * 16B (bf16x32)
    unsigned* h2      = h1 + (size_t)n4 * (HID / 2);          // n4 * 16B

    const int B = 256;
    p1a_count   <<<nblk, 256, 0, stream>>>(dst, counts, E, nbuck, nblk);
    scan1_kernel<<<nbM, SCAN_B, 0, stream>>>(counts, bscan, bsum, M);
    scan2_kernel<<<1, 512, 0, stream>>>(bsum, nbM);
    scan3_kernel<<<nbM, SCAN_B, 0, stream>>>(bscan, counts, bsum, offsets, M);
    bounds_kernel<<<(n + B - 1) / B, B, 0, stream>>>(batch, gstart, n, G);
    p1c_scatter <<<nblk, 256, 0, stream>>>(src, dst, ew, offsets, bkt, E, nbuck, nblk);
    p2_csr      <<<nbuck, BUCK_W, 0, stream>>>(bkt, offsets, csr, rowptr, count, dinv, E, n, nbuck, nblk);
    layer1_kernel<<<(n + B - 1) / B, B, 0, stream>>>(x, rowptr, count, csr, dinv, W1, b1, h1, n);
    layer2_kernel<<<(n + 63) / 64, B, 0, stream>>>(h1, rowptr, count, csr, dinv, W2, b2, h2, n);
    poolheads_kernel<<<(G + 7) / 8, B, 0, stream>>>(h2, gstart, Wo, bo, Wb, bb, out, G);
}

// Round 6
// 130.882 us; speedup vs baseline: 8.6017x; 1.1372x over previous
//
#include <hip/hip_runtime.h>
#include <math.h>

#define FIN 4
#define HID 32
#define SCAN_B 256
#define EPB 4096        // edges per binning block
#define BUCK_SH 9
#define BUCK_W 512      // nodes per bucket

__device__ __forceinline__ unsigned pack_bf16x2(float a, float b) {
    unsigned ua = __float_as_uint(a); ua += 0x7FFF + ((ua >> 16) & 1);
    unsigned ub = __float_as_uint(b); ub += 0x7FFF + ((ub >> 16) & 1);
    return (ua >> 16) | (ub & 0xFFFF0000u);
}

// ---------------------------------------------------------------------------
// 1a) per-block histogram over coarse buckets (LDS only, no global atomics)
__global__ void p1a_count(const int* __restrict__ dst, int* __restrict__ counts,
                          int E, int nbuck, int nblk) {
    __shared__ int h[256];
    int t = threadIdx.x;
    h[t] = 0;
    __syncthreads();
    int base = blockIdx.x * EPB;
    for (int k = t; k < EPB; k += 256) {
        int e = base + k;
        if (e < E) atomicAdd(&h[dst[e] >> BUCK_SH], 1);
    }
    __syncthreads();
    if (t < nbuck) counts[t * nblk + blockIdx.x] = h[t];
}

// ---------------------------------------------------------------------------
// scans (exclusive prefix over counts -> offsets)
__global__ void scan1_kernel(const int* __restrict__ count, int* __restrict__ bscan,
                             int* __restrict__ bsum, int n) {
    __shared__ int s[SCAN_B];
    int i = blockIdx.x * SCAN_B + threadIdx.x;
    int v = (i < n) ? count[i] : 0;
    s[threadIdx.x] = v;
    __syncthreads();
    for (int off = 1; off < SCAN_B; off <<= 1) {
        int t = (threadIdx.x >= off) ? s[threadIdx.x - off] : 0;
        __syncthreads();
        s[threadIdx.x] += t;
        __syncthreads();
    }
    if (i < n) bscan[i] = s[threadIdx.x];
    if (threadIdx.x == SCAN_B - 1) bsum[blockIdx.x] = s[threadIdx.x];
}

__global__ void scan2_kernel(int* __restrict__ data, int nb) {
    __shared__ int s[512];
    __shared__ int carry;
    if (threadIdx.x == 0) carry = 0;
    __syncthreads();
    for (int base = 0; base < nb; base += 512) {
        int idx = base + threadIdx.x;
        int v = (idx < nb) ? data[idx] : 0;
        s[threadIdx.x] = v;
        __syncthreads();
        for (int off = 1; off < 512; off <<= 1) {
            int t = (threadIdx.x >= off) ? s[threadIdx.x - off] : 0;
            __syncthreads();
            s[threadIdx.x] += t;
            __syncthreads();
        }
        int incl = s[threadIdx.x] + carry;
        if (idx < nb) data[idx] = incl;
        __syncthreads();
        if (threadIdx.x == 511) carry = incl;
        __syncthreads();
    }
}

__global__ void scan3_kernel(const int* __restrict__ bscan, const int* __restrict__ count,
                             const int* __restrict__ bsumscan, int* __restrict__ offsets, int n) {
    int i = blockIdx.x * SCAN_B + threadIdx.x;
    if (i >= n) return;
    int off = (blockIdx.x == 0) ? 0 : bsumscan[blockIdx.x - 1];
    offsets[i] = bscan[i] - count[i] + off;
}

// ---------------------------------------------------------------------------
// 1c) scatter edges into per-(bucket,block) regions via LDS cursors
__global__ void p1c_scatter(const int* __restrict__ src, const int* __restrict__ dst,
                            const float* __restrict__ w, const int* __restrict__ offsets,
                            unsigned long long* __restrict__ bkt, int E, int nbuck, int nblk) {
    __shared__ int cur[256];
    int t = threadIdx.x;
    if (t < nbuck) cur[t] = offsets[t * nblk + blockIdx.x];
    __syncthreads();
    int base = blockIdx.x * EPB;
    for (int k = t; k < EPB; k += 256) {
        int e = base + k;
        if (e < E) {
            int d = dst[e];
            int b = d >> BUCK_SH;
            int pos = atomicAdd(&cur[b], 1);
            unsigned hi = ((unsigned)(d & (BUCK_W - 1)) << 17) | (unsigned)src[e];
            bkt[pos] = ((unsigned long long)hi << 32) | (unsigned)__float_as_int(w[e]);
        }
    }
}

// ---------------------------------------------------------------------------
// 2) bucket -> final CSR (src, raw w) + rowptr/count + dinv + xs = dinv*x.
//    One block per bucket; everything via LDS, no global atomics.
__global__ void p2_csr(const unsigned long long* __restrict__ bkt, const int* __restrict__ offsets,
                       const float* __restrict__ x, int2* __restrict__ csr,
                       int* __restrict__ rowptr, int* __restrict__ count,
                       float* __restrict__ dinv, float* __restrict__ xs,
                       int E, int n, int nbuck, int nblk) {
    __shared__ int lcnt[BUCK_W];
    __shared__ int s[BUCK_W];
    __shared__ int curL[BUCK_W];
    __shared__ float wsum[BUCK_W];
    int b = blockIdx.x;
    int t = threadIdx.x;   // 512 threads
    int base = offsets[b * nblk];
    int end  = (b == nbuck - 1) ? E : offsets[(b + 1) * nblk];
    int cnt  = end - base;
    lcnt[t] = 0;
    wsum[t] = 0.f;
    __syncthreads();
    for (int k = t; k < cnt; k += BUCK_W) {
        unsigned hi = (unsigned)(bkt[base + k] >> 32);
        atomicAdd(&lcnt[hi >> 17], 1);
    }
    __syncthreads();
    s[t] = lcnt[t];
    __syncthreads();
    for (int off = 1; off < BUCK_W; off <<= 1) {
        int v = (t >= off) ? s[t - off] : 0;
        __syncthreads();
        s[t] += v;
        __syncthreads();
    }
    int excl = s[t] - lcnt[t];
    curL[t] = excl;
    int node = (b << BUCK_SH) + t;
    if (node < n) { rowptr[node] = base + excl; count[node] = lcnt[t]; }
    __syncthreads();
    for (int k = t; k < cnt; k += BUCK_W) {
        unsigned long long v = bkt[base + k];
        unsigned hi = (unsigned)(v >> 32);
        int ld = hi >> 17;
        int sN = hi & 0x1FFFF;
        float wv = __int_as_float((int)(unsigned)v);
        int p = atomicAdd(&curL[ld], 1);
        csr[base + p] = make_int2(sN, __float_as_int(wv));
        atomicAdd(&wsum[ld], wv);
    }
    __syncthreads();
    if (node < n) {
        float di = rsqrtf(wsum[t] + 1.0f);
        dinv[node] = di;
        float4 xv = *reinterpret_cast<const float4*>(x + (size_t)node * FIN);
        xv.x *= di; xv.y *= di; xv.z *= di; xv.w *= di;
        *reinterpret_cast<float4*>(xs + (size_t)node * FIN) = xv;
    }
}

// ---------------------------------------------------------------------------
// graph segment boundaries from sorted batch
__global__ void bounds_kernel(const int* __restrict__ batch, int* __restrict__ gstart,
                              int n, int G) {
    int i = blockIdx.x * blockDim.x + threadIdx.x;
    if (i >= n) return;
    int b = batch[i];
    if (i == 0) {
        for (int g = 0; g <= b; ++g) gstart[g] = 0;
    } else {
        int p = batch[i - 1];
        for (int g = p + 1; g <= b; ++g) gstart[g] = i;
    }
    if (i == n - 1) {
        for (int g = b + 1; g <= G; ++g) gstart[g] = n;
    }
}

// ---------------------------------------------------------------------------
// layer 1: agg = dinv[i]*(xs[i] + sum w*xs[src]); h1s = dinv[i]*relu(agg@W1+b1)
// csr is read-only (raw w); gathers hit the 1.6MB xs table (L2-resident).
__global__ void layer1_kernel(const float* __restrict__ xs, const int* __restrict__ rowptr,
                              const int* __restrict__ count, const int2* __restrict__ csr,
                              const float* __restrict__ dinv, const float* __restrict__ W1,
                              const float* __restrict__ b1, unsigned* __restrict__ h1, int n) {
    __shared__ float sW[FIN * HID];
    __shared__ float sb[HID];
    int t = threadIdx.x;
    if (t < FIN * HID) sW[t] = W1[t];
    if (t < HID) sb[t] = b1[t];
    __syncthreads();
    int i = blockIdx.x * blockDim.x + t;
    if (i >= n) return;
    float di = dinv[i];
    float4 a = *reinterpret_cast<const float4*>(xs + (size_t)i * FIN);
    int beg = rowptr[i], c = count[i];
    for (int j = 0; j < c; ++j) {
        int2 rec = csr[beg + j];
        float wv = __int_as_float(rec.y);
        float4 v = *reinterpret_cast<const float4*>(xs + (size_t)rec.x * FIN);
        a.x += wv * v.x; a.y += wv * v.y; a.z += wv * v.z; a.w += wv * v.w;
    }
    a.x *= di; a.y *= di; a.z *= di; a.w *= di;
    unsigned* hp = h1 + (size_t)i * (HID / 2);
    #pragma unroll
    for (int k = 0; k < HID; k += 2) {
        float h0 = fmaxf(sb[k]   + a.x*sW[0*HID+k]   + a.y*sW[1*HID+k]   + a.z*sW[2*HID+k]   + a.w*sW[3*HID+k],   0.f);
        float h1v= fmaxf(sb[k+1] + a.x*sW[0*HID+k+1] + a.y*sW[1*HID+k+1] + a.z*sW[2*HID+k+1] + a.w*sW[3*HID+k+1], 0.f);
        hp[k / 2] = pack_bf16x2(di * h0, di * h1v);
    }
}

// ---------------------------------------------------------------------------
// layer 2: acc = h1s[i] + sum w*h1s[src]; agg = dinv[i]*acc; h2 = relu(agg@W2+b2)
__global__ void layer2_kernel(const unsigned* __restrict__ h1, const int* __restrict__ rowptr,
                              const int* __restrict__ count, const int2* __restrict__ csr,
                              const float* __restrict__ dinv, const float* __restrict__ W2,
                              const float* __restrict__ b2, unsigned* __restrict__ h2, int n) {
    __shared__ float sW[HID * HID];
    __shared__ float sb[HID];
    __shared__ float sAgg[64][HID + 1];
    int t = threadIdx.x;
    for (int q = t; q < HID * HID; q += blockDim.x) sW[q] = W2[q];
    if (t < HID) sb[t] = b2[t];
    __syncthreads();
    int nib = t >> 2;          // node-in-block 0..63
    int l   = t & 3;           // 8-dim lane 0..3
    int i = blockIdx.x * 64 + nib;
    const uint4* h1q = reinterpret_cast<const uint4*>(h1);
    float acc[8];
    if (i < n) {
        uint4 hv = h1q[(size_t)i * 4 + l];
        unsigned hw[4] = {hv.x, hv.y, hv.z, hv.w};
        #pragma unroll
        for (int q = 0; q < 4; ++q) {
            acc[q*2]   = __uint_as_float(hw[q] << 16);
            acc[q*2+1] = __uint_as_float(hw[q] & 0xFFFF0000u);
        }
        int beg = rowptr[i], c = count[i];
        int j = 0;
        for (; j + 1 < c; j += 2) {
            int2 r0 = csr[beg + j];
            int2 r1 = csr[beg + j + 1];
            float n0 = __int_as_float(r0.y);
            float n1 = __int_as_float(r1.y);
            uint4 s0 = h1q[(size_t)r0.x * 4 + l];
            uint4 s1 = h1q[(size_t)r1.x * 4 + l];
            unsigned w0[4] = {s0.x, s0.y, s0.z, s0.w};
            unsigned w1[4] = {s1.x, s1.y, s1.z, s1.w};
            #pragma unroll
            for (int q = 0; q < 4; ++q) {
                acc[q*2]   += n0 * __uint_as_float(w0[q] << 16);
                acc[q*2+1] += n0 * __uint_as_float(w0[q] & 0xFFFF0000u);
                acc[q*2]   += n1 * __uint_as_float(w1[q] << 16);
                acc[q*2+1] += n1 * __uint_as_float(w1[q] & 0xFFFF0000u);
            }
        }
        if (j < c) {
            int2 r0 = csr[beg + j];
            float n0 = __int_as_float(r0.y);
            uint4 s0 = h1q[(size_t)r0.x * 4 + l];
            unsigned w0[4] = {s0.x, s0.y, s0.z, s0.w};
            #pragma unroll
            for (int q = 0; q < 4; ++q) {
                acc[q*2]   += n0 * __uint_as_float(w0[q] << 16);
                acc[q*2+1] += n0 * __uint_as_float(w0[q] & 0xFFFF0000u);
            }
        }
        float di = dinv[i];
        #pragma unroll
        for (int q = 0; q < 8; ++q) acc[q] *= di;
    } else {
        #pragma unroll
        for (int q = 0; q < 8; ++q) acc[q] = 0.f;
    }
    #pragma unroll
    for (int q = 0; q < 8; ++q) sAgg[nib][l * 8 + q] = acc[q];
    __syncthreads();
    if (i < n) {
        unsigned outp[4];
        #pragma unroll
        for (int q = 0; q < 4; ++q) {
            int k0 = l * 8 + q * 2;
            float a0 = sb[k0], a1 = sb[k0 + 1];
            #pragma unroll
            for (int j = 0; j < HID; ++j) {
                float av = sAgg[nib][j];
                a0 += av * sW[j * HID + k0];
                a1 += av * sW[j * HID + k0 + 1];
            }
            outp[q] = pack_bf16x2(fmaxf(a0, 0.f), fmaxf(a1, 0.f));
        }
        uint4* h2q = reinterpret_cast<uint4*>(h2);
        h2q[(size_t)i * 4 + l] = make_uint4(outp[0], outp[1], outp[2], outp[3]);
    }
}

// ---------------------------------------------------------------------------
// fused mean-pool + heads: 32 lanes per graph, shuffle reduce
__global__ void poolheads_kernel(const unsigned* __restrict__ h2, const int* __restrict__ gstart,
                                 const float* __restrict__ Wo, const float* __restrict__ bo,
                                 const float* __restrict__ Wb, const float* __restrict__ bb,
                                 float* __restrict__ out, int G) {
    int g = blockIdx.x * 8 + (threadIdx.x >> 5);
    int k = threadIdx.x & 31;
    if (g >= G) return;
    int s0 = gstart[g], s1 = gstart[g + 1];
    float sum = 0.f;
    const unsigned short* h2s = reinterpret_cast<const unsigned short*>(h2);
    for (int i = s0; i < s1; ++i) {
        unsigned u = (unsigned)h2s[(size_t)i * HID + k] << 16;
        sum += __uint_as_float(u);
    }
    float cnt = (float)(s1 - s0);
    float inv = 1.0f / fmaxf(cnt, 1.0f);
    float m = sum * inv;
    float po = m * Wo[k];
    float pb = m * Wb[k];
    #pragma unroll
    for (int off = 16; off >= 1; off >>= 1) {
        po += __shfl_xor(po, off);
        pb += __shfl_xor(pb, off);
    }
    if (k == 0) {
        out[g]     = 1.0f / (1.0f + expf(-(po + bo[0])));
        out[G + g] = 1.0f / (1.0f + expf(-(pb + bb[0])));
    }
}

// ---------------------------------------------------------------------------
extern "C" void kernel_launch(void* const* d_in, const int* in_sizes, int n_in,
                              void* d_out, int out_size, void* d_ws, size_t ws_size,
                              hipStream_t stream) {
    const float* x     = (const float*)d_in[0];
    const int*   ei    = (const int*)d_in[1];
    const float* ew    = (const float*)d_in[2];
    const int*   batch = (const int*)d_in[3];
    const float* W1 = (const float*)d_in[5];
    const float* b1 = (const float*)d_in[6];
    const float* W2 = (const float*)d_in[7];
    const float* b2 = (const float*)d_in[8];
    const float* Wo = (const float*)d_in[9];
    const float* bo = (const float*)d_in[10];
    const float* Wb = (const float*)d_in[11];
    const float* bb = (const float*)d_in[12];
    float* out = (float*)d_out;

    const int n = in_sizes[0] / FIN;   // 100000
    const int E = in_sizes[2];         // 1600000
    const int G = out_size / 2;        // 16384
    const int* src = ei;
    const int* dst = ei + E;
    const int n4 = (n + 3) & ~3;
    const int nblk  = (E + EPB - 1) / EPB;          // binning blocks (391)
    const int nbuck = (n + BUCK_W - 1) / BUCK_W;    // coarse buckets (196)
    const int M  = nbuck * nblk;                    // (bucket,block) counts
    const int Mp = (M + 3) & ~3;
    const int nbM = (M + SCAN_B - 1) / SCAN_B;
    const int nbp = (nbM + 511) & ~511;

    // workspace layout (all regions 16B-aligned)
    char* wsb = (char*)d_ws;
    unsigned long long* bkt = (unsigned long long*)wsb;       // E * 8B
    int2*     csr     = (int2*)(wsb + (size_t)E * 8);         // E * 8B
    int*      counts  = (int*)(wsb + (size_t)E * 16);         // Mp
    int*      offsets = counts + Mp;                          // Mp
    int*      bscan   = offsets + Mp;                         // Mp
    int*      bsum    = bscan + Mp;                           // nbp
    int*      rowptr  = bsum + nbp;                           // n4
    int*      count   = rowptr + n4;                          // n4
    float*    dinv    = (float*)(count + n4);                 // n4
    float*    xs      = dinv + n4;                            // n4*FIN
    int*      gstart  = (int*)(xs + (size_t)n4 * FIN);        // G+16
    unsigned* h1      = (unsigned*)(gstart + G + 16);         // n4 * 16B (bf16x32)
    unsigned* h2      = h1 + (size_t)n4 * (HID / 2);          // n4 * 16B

    const int B = 256;
    p1a_count   <<<nblk, 256, 0, stream>>>(dst, counts, E, nbuck, nblk);
    scan1_kernel<<<nbM, SCAN_B, 0, stream>>>(counts, bscan, bsum, M);
    scan2_kernel<<<1, 512, 0, stream>>>(bsum, nbM);
    scan3_kernel<<<nbM, SCAN_B, 0, stream>>>(bscan, counts, bsum, offsets, M);
    bounds_kernel<<<(n + B - 1) / B, B, 0, stream>>>(batch, gstart, n, G);
    p1c_scatter <<<nblk, 256, 0, stream>>>(src, dst, ew, offsets, bkt, E, nbuck, nblk);
    p2_csr      <<<nbuck, BUCK_W, 0, stream>>>(bkt, offsets, x, csr, rowptr, count, dinv, xs, E, n, nbuck, nblk);
    layer1_kernel<<<(n + B - 1) / B, B, 0, stream>>>(xs, rowptr, count, csr, dinv, W1, b1, h1, n);
    layer2_kernel<<<(n + 63) / 64, B, 0, stream>>>(h1, rowptr, count, csr, dinv, W2, b2, h2, n);
    poolheads_kernel<<<(G + 7) / 8, B, 0, stream>>>(h2, gstart, Wo, bo, Wb, bb, out, G);
}

// Round 7
// 125.489 us; speedup vs baseline: 8.9714x; 1.0430x over previous
//
#include <hip/hip_runtime.h>
#include <math.h>

#define FIN 4
#define HID 32
#define SCAN_B 256
#define EPB 4096        // edges per binning block
#define BUCK_SH 9
#define BUCK_W 512      // nodes per bucket

__device__ __forceinline__ unsigned pack_bf16x2(float a, float b) {
    unsigned ua = __float_as_uint(a); ua += 0x7FFF + ((ua >> 16) & 1);
    unsigned ub = __float_as_uint(b); ub += 0x7FFF + ((ub >> 16) & 1);
    return (ua >> 16) | (ub & 0xFFFF0000u);
}

// ---------------------------------------------------------------------------
// 1a) per-block histogram over coarse buckets (LDS only, no global atomics)
__global__ void p1a_count(const int* __restrict__ dst, int* __restrict__ counts,
                          int E, int nbuck, int nblk) {
    __shared__ int h[256];
    int t = threadIdx.x;
    h[t] = 0;
    __syncthreads();
    int base = blockIdx.x * EPB;
    for (int k = t; k < EPB; k += 256) {
        int e = base + k;
        if (e < E) atomicAdd(&h[dst[e] >> BUCK_SH], 1);
    }
    __syncthreads();
    if (t < nbuck) counts[t * nblk + blockIdx.x] = h[t];
}

// ---------------------------------------------------------------------------
// scans (exclusive prefix over counts -> offsets)
__global__ void scan1_kernel(const int* __restrict__ count, int* __restrict__ bscan,
                             int* __restrict__ bsum, int n) {
    __shared__ int s[SCAN_B];
    int i = blockIdx.x * SCAN_B + threadIdx.x;
    int v = (i < n) ? count[i] : 0;
    s[threadIdx.x] = v;
    __syncthreads();
    for (int off = 1; off < SCAN_B; off <<= 1) {
        int t = (threadIdx.x >= off) ? s[threadIdx.x - off] : 0;
        __syncthreads();
        s[threadIdx.x] += t;
        __syncthreads();
    }
    if (i < n) bscan[i] = s[threadIdx.x];
    if (threadIdx.x == SCAN_B - 1) bsum[blockIdx.x] = s[threadIdx.x];
}

__global__ void scan2_kernel(int* __restrict__ data, int nb) {
    __shared__ int s[512];
    __shared__ int carry;
    if (threadIdx.x == 0) carry = 0;
    __syncthreads();
    for (int base = 0; base < nb; base += 512) {
        int idx = base + threadIdx.x;
        int v = (idx < nb) ? data[idx] : 0;
        s[threadIdx.x] = v;
        __syncthreads();
        for (int off = 1; off < 512; off <<= 1) {
            int t = (threadIdx.x >= off) ? s[threadIdx.x - off] : 0;
            __syncthreads();
            s[threadIdx.x] += t;
            __syncthreads();
        }
        int incl = s[threadIdx.x] + carry;
        if (idx < nb) data[idx] = incl;
        __syncthreads();
        if (threadIdx.x == 511) carry = incl;
        __syncthreads();
    }
}

__global__ void scan3_kernel(const int* __restrict__ bscan, const int* __restrict__ count,
                             const int* __restrict__ bsumscan, int* __restrict__ offsets, int n) {
    int i = blockIdx.x * SCAN_B + threadIdx.x;
    if (i >= n) return;
    int off = (blockIdx.x == 0) ? 0 : bsumscan[blockIdx.x - 1];
    offsets[i] = bscan[i] - count[i] + off;
}

// ---------------------------------------------------------------------------
// 1c) scatter edges into per-(bucket,block) regions via LDS cursors
__global__ void p1c_scatter(const int* __restrict__ src, const int* __restrict__ dst,
                            const float* __restrict__ w, const int* __restrict__ offsets,
                            unsigned long long* __restrict__ bkt, int E, int nbuck, int nblk) {
    __shared__ int cur[256];
    int t = threadIdx.x;
    if (t < nbuck) cur[t] = offsets[t * nblk + blockIdx.x];
    __syncthreads();
    int base = blockIdx.x * EPB;
    for (int k = t; k < EPB; k += 256) {
        int e = base + k;
        if (e < E) {
            int d = dst[e];
            int b = d >> BUCK_SH;
            int pos = atomicAdd(&cur[b], 1);
            unsigned hi = ((unsigned)(d & (BUCK_W - 1)) << 17) | (unsigned)src[e];
            bkt[pos] = ((unsigned long long)hi << 32) | (unsigned)__float_as_int(w[e]);
        }
    }
}

// ---------------------------------------------------------------------------
// 2) bucket -> final CSR (src, raw w) + rowptr/count + dinv + xs = dinv*x.
//    One block per bucket; everything via LDS, no global atomics.
__global__ void p2_csr(const unsigned long long* __restrict__ bkt, const int* __restrict__ offsets,
                       const float* __restrict__ x, int2* __restrict__ csr,
                       int* __restrict__ rowptr, int* __restrict__ count,
                       float* __restrict__ dinv, float* __restrict__ xs,
                       int E, int n, int nbuck, int nblk) {
    __shared__ int lcnt[BUCK_W];
    __shared__ int s[BUCK_W];
    __shared__ int curL[BUCK_W];
    __shared__ float wsum[BUCK_W];
    int b = blockIdx.x;
    int t = threadIdx.x;   // 512 threads
    int base = offsets[b * nblk];
    int end  = (b == nbuck - 1) ? E : offsets[(b + 1) * nblk];
    int cnt  = end - base;
    lcnt[t] = 0;
    wsum[t] = 0.f;
    __syncthreads();
    for (int k = t; k < cnt; k += BUCK_W) {
        unsigned hi = (unsigned)(bkt[base + k] >> 32);
        atomicAdd(&lcnt[hi >> 17], 1);
    }
    __syncthreads();
    s[t] = lcnt[t];
    __syncthreads();
    for (int off = 1; off < BUCK_W; off <<= 1) {
        int v = (t >= off) ? s[t - off] : 0;
        __syncthreads();
        s[t] += v;
        __syncthreads();
    }
    int excl = s[t] - lcnt[t];
    curL[t] = excl;
    int node = (b << BUCK_SH) + t;
    if (node < n) { rowptr[node] = base + excl; count[node] = lcnt[t]; }
    __syncthreads();
    for (int k = t; k < cnt; k += BUCK_W) {
        unsigned long long v = bkt[base + k];
        unsigned hi = (unsigned)(v >> 32);
        int ld = hi >> 17;
        int sN = hi & 0x1FFFF;
        float wv = __int_as_float((int)(unsigned)v);
        int p = atomicAdd(&curL[ld], 1);
        csr[base + p] = make_int2(sN, __float_as_int(wv));
        atomicAdd(&wsum[ld], wv);
    }
    __syncthreads();
    if (node < n) {
        float di = rsqrtf(wsum[t] + 1.0f);
        dinv[node] = di;
        float4 xv = *reinterpret_cast<const float4*>(x + (size_t)node * FIN);
        xv.x *= di; xv.y *= di; xv.z *= di; xv.w *= di;
        *reinterpret_cast<float4*>(xs + (size_t)node * FIN) = xv;
    }
}

// ---------------------------------------------------------------------------
// graph segment boundaries from sorted batch
__global__ void bounds_kernel(const int* __restrict__ batch, int* __restrict__ gstart,
                              int n, int G) {
    int i = blockIdx.x * blockDim.x + threadIdx.x;
    if (i >= n) return;
    int b = batch[i];
    if (i == 0) {
        for (int g = 0; g <= b; ++g) gstart[g] = 0;
    } else {
        int p = batch[i - 1];
        for (int g = p + 1; g <= b; ++g) gstart[g] = i;
    }
    if (i == n - 1) {
        for (int g = b + 1; g <= G; ++g) gstart[g] = n;
    }
}

// ---------------------------------------------------------------------------
// layer 1: agg = dinv[i]*(xs[i] + sum w*xs[src]); h1s = dinv[i]*relu(agg@W1+b1)
__global__ void layer1_kernel(const float* __restrict__ xs, const int* __restrict__ rowptr,
                              const int* __restrict__ count, const int2* __restrict__ csr,
                              const float* __restrict__ dinv, const float* __restrict__ W1,
                              const float* __restrict__ b1, unsigned* __restrict__ h1, int n) {
    __shared__ float sW[FIN * HID];
    __shared__ float sb[HID];
    int t = threadIdx.x;
    if (t < FIN * HID) sW[t] = W1[t];
    if (t < HID) sb[t] = b1[t];
    __syncthreads();
    int i = blockIdx.x * blockDim.x + t;
    if (i >= n) return;
    float di = dinv[i];
    float4 a = *reinterpret_cast<const float4*>(xs + (size_t)i * FIN);
    int beg = rowptr[i], c = count[i];
    for (int j = 0; j < c; ++j) {
        int2 rec = csr[beg + j];
        float wv = __int_as_float(rec.y);
        float4 v = *reinterpret_cast<const float4*>(xs + (size_t)rec.x * FIN);
        a.x += wv * v.x; a.y += wv * v.y; a.z += wv * v.z; a.w += wv * v.w;
    }
    a.x *= di; a.y *= di; a.z *= di; a.w *= di;
    unsigned* hp = h1 + (size_t)i * (HID / 2);
    #pragma unroll
    for (int k = 0; k < HID; k += 2) {
        float h0 = fmaxf(sb[k]   + a.x*sW[0*HID+k]   + a.y*sW[1*HID+k]   + a.z*sW[2*HID+k]   + a.w*sW[3*HID+k],   0.f);
        float h1v= fmaxf(sb[k+1] + a.x*sW[0*HID+k+1] + a.y*sW[1*HID+k+1] + a.z*sW[2*HID+k+1] + a.w*sW[3*HID+k+1], 0.f);
        hp[k / 2] = pack_bf16x2(di * h0, di * h1v);
    }
}

// ---------------------------------------------------------------------------
// layer 2: 8 lanes/node, uint2 (8B) gathers, edge loop unrolled x4.
// acc = h1s[i] + sum w*h1s[src]; agg = dinv[i]*acc; h2 = relu(agg@W2+b2)
__global__ void layer2_kernel(const unsigned* __restrict__ h1, const int* __restrict__ rowptr,
                              const int* __restrict__ count, const int2* __restrict__ csr,
                              const float* __restrict__ dinv, const float* __restrict__ W2,
                              const float* __restrict__ b2, unsigned* __restrict__ h2, int n) {
    __shared__ float sW[HID * HID];
    __shared__ float sb[HID];
    __shared__ float sAgg[32][HID + 1];
    int t = threadIdx.x;
    for (int q = t; q < HID * HID; q += blockDim.x) sW[q] = W2[q];
    if (t < HID) sb[t] = b2[t];
    __syncthreads();
    int nib = t >> 3;          // node-in-block 0..31
    int l   = t & 7;           // 4-dim lane 0..7
    int i = blockIdx.x * 32 + nib;
    const uint2* h1d = reinterpret_cast<const uint2*>(h1);   // row = 8 uint2
    float a0, a1, a2, a3;
    if (i < n) {
        uint2 hv = h1d[(size_t)i * 8 + l];
        a0 = __uint_as_float(hv.x << 16);
        a1 = __uint_as_float(hv.x & 0xFFFF0000u);
        a2 = __uint_as_float(hv.y << 16);
        a3 = __uint_as_float(hv.y & 0xFFFF0000u);
        int beg = rowptr[i], c = count[i];
        int j = 0;
        for (; j + 3 < c; j += 4) {
            int2 r0 = csr[beg + j];
            int2 r1 = csr[beg + j + 1];
            int2 r2 = csr[beg + j + 2];
            int2 r3 = csr[beg + j + 3];
            uint2 s0 = h1d[(size_t)r0.x * 8 + l];
            uint2 s1 = h1d[(size_t)r1.x * 8 + l];
            uint2 s2 = h1d[(size_t)r2.x * 8 + l];
            uint2 s3 = h1d[(size_t)r3.x * 8 + l];
            float n0 = __int_as_float(r0.y), n1 = __int_as_float(r1.y);
            float n2 = __int_as_float(r2.y), n3 = __int_as_float(r3.y);
            a0 += n0 * __uint_as_float(s0.x << 16);
            a1 += n0 * __uint_as_float(s0.x & 0xFFFF0000u);
            a2 += n0 * __uint_as_float(s0.y << 16);
            a3 += n0 * __uint_as_float(s0.y & 0xFFFF0000u);
            a0 += n1 * __uint_as_float(s1.x << 16);
            a1 += n1 * __uint_as_float(s1.x & 0xFFFF0000u);
            a2 += n1 * __uint_as_float(s1.y << 16);
            a3 += n1 * __uint_as_float(s1.y & 0xFFFF0000u);
            a0 += n2 * __uint_as_float(s2.x << 16);
            a1 += n2 * __uint_as_float(s2.x & 0xFFFF0000u);
            a2 += n2 * __uint_as_float(s2.y << 16);
            a3 += n2 * __uint_as_float(s2.y & 0xFFFF0000u);
            a0 += n3 * __uint_as_float(s3.x << 16);
            a1 += n3 * __uint_as_float(s3.x & 0xFFFF0000u);
            a2 += n3 * __uint_as_float(s3.y << 16);
            a3 += n3 * __uint_as_float(s3.y & 0xFFFF0000u);
        }
        for (; j < c; ++j) {
            int2 r0 = csr[beg + j];
            float n0 = __int_as_float(r0.y);
            uint2 s0 = h1d[(size_t)r0.x * 8 + l];
            a0 += n0 * __uint_as_float(s0.x << 16);
            a1 += n0 * __uint_as_float(s0.x & 0xFFFF0000u);
            a2 += n0 * __uint_as_float(s0.y << 16);
            a3 += n0 * __uint_as_float(s0.y & 0xFFFF0000u);
        }
        float di = dinv[i];
        a0 *= di; a1 *= di; a2 *= di; a3 *= di;
    } else {
        a0 = a1 = a2 = a3 = 0.f;
    }
    sAgg[nib][l * 4 + 0] = a0;
    sAgg[nib][l * 4 + 1] = a1;
    sAgg[nib][l * 4 + 2] = a2;
    sAgg[nib][l * 4 + 3] = a3;
    __syncthreads();
    if (i < n) {
        int k0 = l * 4;
        float o0 = sb[k0], o1 = sb[k0 + 1], o2 = sb[k0 + 2], o3 = sb[k0 + 3];
        #pragma unroll
        for (int j = 0; j < HID; ++j) {
            float av = sAgg[nib][j];
            o0 += av * sW[j * HID + k0];
            o1 += av * sW[j * HID + k0 + 1];
            o2 += av * sW[j * HID + k0 + 2];
            o3 += av * sW[j * HID + k0 + 3];
        }
        uint2 packed;
        packed.x = pack_bf16x2(fmaxf(o0, 0.f), fmaxf(o1, 0.f));
        packed.y = pack_bf16x2(fmaxf(o2, 0.f), fmaxf(o3, 0.f));
        uint2* h2d = reinterpret_cast<uint2*>(h2);
        h2d[(size_t)i * 8 + l] = packed;
    }
}

// ---------------------------------------------------------------------------
// fused mean-pool + heads: 32 lanes per graph, shuffle reduce
__global__ void poolheads_kernel(const unsigned* __restrict__ h2, const int* __restrict__ gstart,
                                 const float* __restrict__ Wo, const float* __restrict__ bo,
                                 const float* __restrict__ Wb, const float* __restrict__ bb,
                                 float* __restrict__ out, int G) {
    int g = blockIdx.x * 8 + (threadIdx.x >> 5);
    int k = threadIdx.x & 31;
    if (g >= G) return;
    int s0 = gstart[g], s1 = gstart[g + 1];
    float sum = 0.f;
    const unsigned short* h2s = reinterpret_cast<const unsigned short*>(h2);
    for (int i = s0; i < s1; ++i) {
        unsigned u = (unsigned)h2s[(size_t)i * HID + k] << 16;
        sum += __uint_as_float(u);
    }
    float cnt = (float)(s1 - s0);
    float inv = 1.0f / fmaxf(cnt, 1.0f);
    float m = sum * inv;
    float po = m * Wo[k];
    float pb = m * Wb[k];
    #pragma unroll
    for (int off = 16; off >= 1; off >>= 1) {
        po += __shfl_xor(po, off);
        pb += __shfl_xor(pb, off);
    }
    if (k == 0) {
        out[g]     = 1.0f / (1.0f + expf(-(po + bo[0])));
        out[G + g] = 1.0f / (1.0f + expf(-(pb + bb[0])));
    }
}

// ---------------------------------------------------------------------------
extern "C" void kernel_launch(void* const* d_in, const int* in_sizes, int n_in,
                              void* d_out, int out_size, void* d_ws, size_t ws_size,
                              hipStream_t stream) {
    const float* x     = (const float*)d_in[0];
    const int*   ei    = (const int*)d_in[1];
    const float* ew    = (const float*)d_in[2];
    const int*   batch = (const int*)d_in[3];
    const float* W1 = (const float*)d_in[5];
    const float* b1 = (const float*)d_in[6];
    const float* W2 = (const float*)d_in[7];
    const float* b2 = (const float*)d_in[8];
    const float* Wo = (const float*)d_in[9];
    const float* bo = (const float*)d_in[10];
    const float* Wb = (const float*)d_in[11];
    const float* bb = (const float*)d_in[12];
    float* out = (float*)d_out;

    const int n = in_sizes[0] / FIN;   // 100000
    const int E = in_sizes[2];         // 1600000
    const int G = out_size / 2;        // 16384
    const int* src = ei;
    const int* dst = ei + E;
    const int n4 = (n + 3) & ~3;
    const int nblk  = (E + EPB - 1) / EPB;          // binning blocks (391)
    const int nbuck = (n + BUCK_W - 1) / BUCK_W;    // coarse buckets (196)
    const int M  = nbuck * nblk;                    // (bucket,block) counts
    const int Mp = (M + 3) & ~3;
    const int nbM = (M + SCAN_B - 1) / SCAN_B;
    const int nbp = (nbM + 511) & ~511;

    // workspace layout (all regions 16B-aligned)
    char* wsb = (char*)d_ws;
    unsigned long long* bkt = (unsigned long long*)wsb;       // E * 8B
    int2*     csr     = (int2*)(wsb + (size_t)E * 8);         // E * 8B
    int*      counts  = (int*)(wsb + (size_t)E * 16);         // Mp
    int*      offsets = counts + Mp;                          // Mp
    int*      bscan   = offsets + Mp;                         // Mp
    int*      bsum    = bscan + Mp;                           // nbp
    int*      rowptr  = bsum + nbp;                           // n4
    int*      count   = rowptr + n4;                          // n4
    float*    dinv    = (float*)(count + n4);                 // n4
    float*    xs      = dinv + n4;                            // n4*FIN
    int*      gstart  = (int*)(xs + (size_t)n4 * FIN);        // G+16
    unsigned* h1      = (unsigned*)(gstart + G + 16);         // n4 * 16B (bf16x32)
    unsigned* h2      = h1 + (size_t)n4 * (HID / 2);          // n4 * 16B

    const int B = 256;
    p1a_count   <<<nblk, 256, 0, stream>>>(dst, counts, E, nbuck, nblk);
    scan1_kernel<<<nbM, SCAN_B, 0, stream>>>(counts, bscan, bsum, M);
    scan2_kernel<<<1, 512, 0, stream>>>(bsum, nbM);
    scan3_kernel<<<nbM, SCAN_B, 0, stream>>>(bscan, counts, bsum, offsets, M);
    bounds_kernel<<<(n + B - 1) / B, B, 0, stream>>>(batch, gstart, n, G);
    p1c_scatter <<<nblk, 256, 0, stream>>>(src, dst, ew, offsets, bkt, E, nbuck, nblk);
    p2_csr      <<<nbuck, BUCK_W, 0, stream>>>(bkt, offsets, x, csr, rowptr, count, dinv, xs, E, n, nbuck, nblk);
    layer1_kernel<<<(n + B - 1) / B, B, 0, stream>>>(xs, rowptr, count, csr, dinv, W1, b1, h1, n);
    layer2_kernel<<<(n + 31) / 32, B, 0, stream>>>(h1, rowptr, count, csr, dinv, W2, b2, h2, n);
    poolheads_kernel<<<(G + 7) / 8, B, 0, stream>>>(h2, gstart, Wo, bo, Wb, bb, out, G);
}